// Round 1
// baseline (1050.293 us; speedup 1.0000x reference)
//
#include <hip/hip_runtime.h>

// MLA v3 forward, MI355X/gfx950.
// Pipeline: fp32->bf16 convert -> bf16 MFMA GEMMs (16x16x32) -> rope/assemble
//           -> flash attention (online softmax) -> output GEMM (fp32 out).
// Assumptions to re-verify in round 1: d_in/d_out are fp32; ws_size >= ~139MB.

typedef unsigned short u16;
typedef __attribute__((ext_vector_type(8))) short s16x8;
typedef __attribute__((ext_vector_type(4))) float f32x4;
typedef __attribute__((ext_vector_type(8))) __bf16 bf16x8;
typedef __attribute__((ext_vector_type(4))) u16 u16x4;

#define S_LEN 2048
#define NH 16
#define HD 128
#define DQK 192
#define EMB 2048

__device__ __forceinline__ u16 f2b(float f) {
  unsigned u = __builtin_bit_cast(unsigned, f);
  u += 0x7FFFu + ((u >> 16) & 1u);           // RNE to bf16
  return (u16)(u >> 16);
}
__device__ __forceinline__ float b2f(u16 v) {
  unsigned u = ((unsigned)v) << 16;
  return __builtin_bit_cast(float, u);
}
__device__ __forceinline__ bf16x8 ld_bf8(const u16* p) {
  return __builtin_bit_cast(bf16x8, *(const s16x8*)p);
}

__global__ __launch_bounds__(256) void f2b_kernel(const float* __restrict__ in,
                                                  u16* __restrict__ out, int n4) {
  int i = blockIdx.x * 256 + threadIdx.x;
  if (i >= n4) return;
  f32x4 v = *(const f32x4*)(in + (size_t)i * 4);
  u16x4 o = { f2b(v[0]), f2b(v[1]), f2b(v[2]), f2b(v[3]) };
  *(u16x4*)(out + (size_t)i * 4) = o;
}

__global__ __launch_bounds__(256) void rope_table_kernel(float* __restrict__ cosT,
                                                         float* __restrict__ sinT) {
  int id = blockIdx.x * 256 + threadIdx.x;   // S_LEN*32 = 65536
  int s = id >> 5, i = id & 31;
  // inv_freq = 10000^(-2i/64) = 2^(-i/32 * log2(10000))
  float inv = exp2f(-(float)i * (13.287712379549449f / 32.0f));
  float ang = (float)s * inv;
  cosT[id] = cosf(ang);
  sinT[id] = sinf(ang);
}

// C = A[M,K] @ B[K,N], A/B bf16 row-major, fp32 accum.
// MODE 0: bf16 [M,N]; MODE 1: fp32 [M,N]; MODE 2: bf16 head-major
//   [B][H][S][ostride] slice cols 0..127 (h = col>>7, d = col&127), scaled.
template<int MODE>
__global__ __launch_bounds__(256) void gemm_kernel(const u16* __restrict__ A,
                                                   const u16* __restrict__ B,
                                                   void* __restrict__ Cout,
                                                   int M, int N, int K,
                                                   int ostride, float scale) {
  __shared__ u16 As[128][40];   // [row][k], +8 pad
  __shared__ u16 Bs[128][40];   // transposed: [col][k], +8 pad
  const int t = threadIdx.x;
  const int lane = t & 63, wid = t >> 6;
  const int wr = (wid >> 1) * 64, wc = (wid & 1) * 64;
  const int bm0 = blockIdx.y * 128, bn0 = blockIdx.x * 128;
  const int lr = lane & 15, lg = lane >> 4;

  f32x4 acc[4][4] = {};

  for (int k0 = 0; k0 < K; k0 += 32) {
    __syncthreads();
#pragma unroll
    for (int r = 0; r < 2; ++r) {           // stage A: 128x32
      int chunk = t + r * 256;
      int row = chunk >> 2, cc = chunk & 3;
      s16x8 av = *(const s16x8*)(A + (size_t)(bm0 + row) * K + k0 + cc * 8);
      *(s16x8*)(&As[row][cc * 8]) = av;
    }
#pragma unroll
    for (int r = 0; r < 2; ++r) {           // stage B transposed: 32x128 -> [col][k]
      int chunk = t + r * 256;
      int krow = chunk >> 4, cc = chunk & 15;
      int col = bn0 + cc * 8;
      s16x8 bv = { 0, 0, 0, 0, 0, 0, 0, 0 };
      if (col < N) bv = *(const s16x8*)(B + (size_t)(k0 + krow) * N + col);
#pragma unroll
      for (int e = 0; e < 8; ++e) Bs[cc * 8 + e][krow] = (u16)bv[e];
    }
    __syncthreads();

    bf16x8 af[4], bfr[4];
#pragma unroll
    for (int m = 0; m < 4; ++m) af[m] = ld_bf8(&As[wr + m * 16 + lr][lg * 8]);
#pragma unroll
    for (int n = 0; n < 4; ++n) bfr[n] = ld_bf8(&Bs[wc + n * 16 + lr][lg * 8]);
#pragma unroll
    for (int m = 0; m < 4; ++m)
#pragma unroll
      for (int n = 0; n < 4; ++n)
        acc[m][n] = __builtin_amdgcn_mfma_f32_16x16x32_bf16(af[m], bfr[n], acc[m][n], 0, 0, 0);
  }

  // C/D layout: col = lane&15, row = (lane>>4)*4 + reg  [m89-verified]
#pragma unroll
  for (int m = 0; m < 4; ++m)
#pragma unroll
    for (int n = 0; n < 4; ++n)
#pragma unroll
      for (int rg = 0; rg < 4; ++rg) {
        int row = bm0 + wr + m * 16 + lg * 4 + rg;
        int col = bn0 + wc + n * 16 + lr;
        if (col >= N) continue;
        float v = acc[m][n][rg] * scale;
        if (MODE == 0) {
          ((u16*)Cout)[(size_t)row * N + col] = f2b(v);
        } else if (MODE == 1) {
          ((float*)Cout)[(size_t)row * N + col] = v;
        } else {
          int bb = row >> 11, s = row & 2047;     // M rows = b*S+s, S=2048
          int h = col >> 7, d = col & 127;
          ((u16*)Cout)[((size_t)(bb * NH + h) * S_LEN + s) * (size_t)ostride + d] = f2b(v);
        }
      }
}

// Fill rope halves: Qcat[..,128..191] = SCALE*rope(q_r), Kcat[..,128..191] = rope(k_r)
__global__ __launch_bounds__(256) void rope_assemble_kernel(const u16* __restrict__ qr,
                                                            const u16* __restrict__ kr,
                                                            const float* __restrict__ cosT,
                                                            const float* __restrict__ sinT,
                                                            u16* __restrict__ Qcat,
                                                            u16* __restrict__ Kcat) {
  int id = blockIdx.x * 256 + threadIdx.x;   // B*H*S*32 = 2^21
  int i = id & 31;
  int s = (id >> 5) & 2047;
  int h = (id >> 16) & 15;
  int b = id >> 20;
  float c = cosT[(s << 5) + i], sn = sinT[(s << 5) + i];
  const float SC = 0.07216878364870323f;     // 1/sqrt(192)

  size_t qbase = ((size_t)b * S_LEN + s) * 1024 + h * 64 + 2 * i;
  float qe = b2f(qr[qbase]), qo = b2f(qr[qbase + 1]);
  size_t obase = ((size_t)(b * NH + h) * S_LEN + s) * DQK + HD + 2 * i;
  Qcat[obase]     = f2b((qe * c - qo * sn) * SC);
  Qcat[obase + 1] = f2b((qe * sn + qo * c) * SC);

  size_t kbase = ((size_t)b * S_LEN + s) * 64 + 2 * i;
  float ke = b2f(kr[kbase]), ko = b2f(kr[kbase + 1]);
  Kcat[obase]     = f2b(ke * c - ko * sn);
  Kcat[obase + 1] = f2b(ke * sn + ko * c);
}

// Flash attention, causal. Q,K: [B][H][S][192] bf16 (Q pre-scaled); V: [B][H][S][128].
// Block = 256 thr (4 waves), 64 q-rows/block (16/wave), kv tiles of 64.
__global__ __launch_bounds__(256) void attn_kernel(const u16* __restrict__ Q,
                                                   const u16* __restrict__ K,
                                                   const u16* __restrict__ V,
                                                   u16* __restrict__ O) {
  __shared__ u16 Ks[64][200];    // [kv][d], +8 pad
  __shared__ u16 Vt[128][80];    // transposed [d][kv], +16 pad (16B-aligned rows)
  __shared__ u16 Ps[4][16][80];  // per-wave P tile [q][kv]
  const int qb = blockIdx.x, h = blockIdx.y, b = blockIdx.z;
  const int t = threadIdx.x, lane = t & 63, wid = t >> 6;
  const int lr = lane & 15, lg = lane >> 4;
  const size_t qk_head = (size_t)(b * NH + h) * S_LEN * DQK;
  const size_t v_head  = (size_t)(b * NH + h) * S_LEN * HD;

  // Q fragments in registers (wave's 16 rows x 192)
  bf16x8 qa[6];
  {
    const u16* qrow = Q + qk_head + (size_t)(qb * 64 + wid * 16 + lr) * DQK;
#pragma unroll
    for (int ks = 0; ks < 6; ++ks) qa[ks] = ld_bf8(qrow + ks * 32 + lg * 8);
  }

  f32x4 acc_o[8] = {};
  float m_r[4] = { -INFINITY, -INFINITY, -INFINITY, -INFINITY };
  float l_r[4] = { 0.f, 0.f, 0.f, 0.f };

  const int nt = qb + 1;
  for (int kt = 0; kt < nt; ++kt) {
    __syncthreads();
#pragma unroll
    for (int r = 0; r < 6; ++r) {          // stage K tile 64x192
      int chunk = t + r * 256;
      int row = chunk / 24, cc = chunk % 24;
      s16x8 v = *(const s16x8*)(K + qk_head + (size_t)(kt * 64 + row) * DQK + cc * 8);
      *(s16x8*)(&Ks[row][cc * 8]) = v;
    }
#pragma unroll
    for (int r = 0; r < 4; ++r) {          // stage V^T 64x128 -> [d][kv]
      int chunk = t + r * 256;
      int kv = chunk >> 4, cc = chunk & 15;
      s16x8 v = *(const s16x8*)(V + v_head + (size_t)(kt * 64 + kv) * HD + cc * 8);
#pragma unroll
      for (int e = 0; e < 8; ++e) Vt[cc * 8 + e][kv] = (u16)v[e];
    }
    __syncthreads();

    // S = Q K^T  (A=Q 16x32, B=K^T: lane col=kv(lr), k=d)
    f32x4 sacc[4];
#pragma unroll
    for (int cb = 0; cb < 4; ++cb) {
      f32x4 sv = {};
#pragma unroll
      for (int ks = 0; ks < 6; ++ks) {
        bf16x8 kb = ld_bf8(&Ks[cb * 16 + lr][ks * 32 + lg * 8]);
        sv = __builtin_amdgcn_mfma_f32_16x16x32_bf16(qa[ks], kb, sv, 0, 0, 0);
      }
      sacc[cb] = sv;
    }

    if (kt == qb) {                        // diagonal tile causal mask
#pragma unroll
      for (int cb = 0; cb < 4; ++cb)
#pragma unroll
        for (int rg = 0; rg < 4; ++rg) {
          int q_loc = wid * 16 + lg * 4 + rg;
          int kv_loc = cb * 16 + lr;
          if (kv_loc > q_loc) sacc[cb][rg] = -INFINITY;
        }
    }

    // row max across 16 lanes of the lane-group (rows = lg*4+rg)
    float pmax[4];
#pragma unroll
    for (int rg = 0; rg < 4; ++rg)
      pmax[rg] = fmaxf(fmaxf(sacc[0][rg], sacc[1][rg]), fmaxf(sacc[2][rg], sacc[3][rg]));
#pragma unroll
    for (int off = 1; off < 16; off <<= 1)
#pragma unroll
      for (int rg = 0; rg < 4; ++rg)
        pmax[rg] = fmaxf(pmax[rg], __shfl_xor(pmax[rg], off, 64));

    float alpha[4];
#pragma unroll
    for (int rg = 0; rg < 4; ++rg) {
      float mn = fmaxf(m_r[rg], pmax[rg]);
      alpha[rg] = __expf(m_r[rg] - mn);
      m_r[rg] = mn;
      l_r[rg] *= alpha[rg];
    }
#pragma unroll
    for (int vb = 0; vb < 8; ++vb)
#pragma unroll
      for (int rg = 0; rg < 4; ++rg)
        acc_o[vb][rg] *= alpha[rg];

    float psum[4] = { 0.f, 0.f, 0.f, 0.f };
#pragma unroll
    for (int cb = 0; cb < 4; ++cb)
#pragma unroll
      for (int rg = 0; rg < 4; ++rg) {
        float p = __expf(sacc[cb][rg] - m_r[rg]);
        sacc[cb][rg] = p;
        psum[rg] += p;
      }
#pragma unroll
    for (int off = 1; off < 16; off <<= 1)
#pragma unroll
      for (int rg = 0; rg < 4; ++rg)
        psum[rg] += __shfl_xor(psum[rg], off, 64);
#pragma unroll
    for (int rg = 0; rg < 4; ++rg) l_r[rg] += psum[rg];

    // P -> LDS (per-wave region; same-wave RAW, no barrier needed)
#pragma unroll
    for (int cb = 0; cb < 4; ++cb)
#pragma unroll
      for (int rg = 0; rg < 4; ++rg)
        Ps[wid][lg * 4 + rg][cb * 16 + lr] = f2b(sacc[cb][rg]);

    bf16x8 pa[2];
#pragma unroll
    for (int ks = 0; ks < 2; ++ks) pa[ks] = ld_bf8(&Ps[wid][lr][ks * 32 + lg * 8]);
#pragma unroll
    for (int vb = 0; vb < 8; ++vb) {
#pragma unroll
      for (int ks = 0; ks < 2; ++ks) {
        bf16x8 vv = ld_bf8(&Vt[vb * 16 + lr][ks * 32 + lg * 8]);
        acc_o[vb] = __builtin_amdgcn_mfma_f32_16x16x32_bf16(pa[ks], vv, acc_o[vb], 0, 0, 0);
      }
    }
  }

  // epilogue: O[b][s][h*128+d] bf16
#pragma unroll
  for (int vb = 0; vb < 8; ++vb)
#pragma unroll
    for (int rg = 0; rg < 4; ++rg) {
      int s_glob = qb * 64 + wid * 16 + lg * 4 + rg;
      int col = vb * 16 + lr;
      O[((size_t)b * S_LEN + s_glob) * EMB + h * HD + col] = f2b(acc_o[vb][rg] / l_r[rg]);
    }
}

extern "C" void kernel_launch(void* const* d_in, const int* in_sizes, int n_in,
                              void* d_out, int out_size, void* d_ws, size_t ws_size,
                              hipStream_t stream) {
  const float* xf    = (const float*)d_in[0];
  const float* wckvf = (const float*)d_in[1];
  const float* wkf   = (const float*)d_in[2];
  const float* wvf   = (const float*)d_in[3];
  const float* wcqf  = (const float*)d_in[4];
  const float* wqf   = (const float*)d_in[5];
  const float* wqrf  = (const float*)d_in[6];
  const float* wkrf  = (const float*)d_in[7];
  const float* wof   = (const float*)d_in[8];
  (void)in_sizes; (void)n_in; (void)out_size; (void)ws_size;

  u16* ws = (u16*)d_ws;
  size_t off = 0;
  auto alloc = [&](size_t n) -> u16* { u16* p = ws + off; off += n; return p; };
  u16* XB   = alloc(8388608);   // x bf16 [4096,2048]
  u16* WCKV = alloc(1048576);
  u16* WK   = alloc(1048576);
  u16* WV   = alloc(1048576);
  u16* WCQ  = alloc(1048576);
  u16* WQ   = alloc(1048576);
  u16* WQR  = alloc(524288);
  u16* WKR  = alloc(131072);
  u16* WO   = alloc(4194304);
  u16* CKV  = alloc(2097152);   // [4096,512]
  u16* CQ   = alloc(2097152);
  u16* QR   = alloc(4194304);   // [4096,1024]
  u16* KR   = alloc(262144);    // [4096,64]
  u16* QCAT = alloc(12582912);  // [B,H,S,192]
  u16* KCAT = alloc(12582912);
  u16* VH   = alloc(8388608);   // [B,H,S,128]
  u16* AOUT = alloc(8388608);   // [4096,2048]
  float* COS_T = (float*)alloc(131072);  // 65536 floats
  float* SIN_T = (float*)alloc(131072);
  // total ws: ~138.7 MB

  auto cvt = [&](const float* src, u16* dst, int n) {
    int n4 = n / 4;
    f2b_kernel<<<(n4 + 255) / 256, 256, 0, stream>>>(src, dst, n4);
  };
  cvt(xf, XB, 8388608);
  cvt(wckvf, WCKV, 1048576);
  cvt(wkf, WK, 1048576);
  cvt(wvf, WV, 1048576);
  cvt(wcqf, WCQ, 1048576);
  cvt(wqf, WQ, 1048576);
  cvt(wqrf, WQR, 524288);
  cvt(wkrf, WKR, 131072);
  cvt(wof, WO, 4194304);

  rope_table_kernel<<<256, 256, 0, stream>>>(COS_T, SIN_T);

  const float SC = 0.07216878364870323f;  // 1/sqrt(192)
  gemm_kernel<0><<<dim3(4, 32), 256, 0, stream>>>(XB, WCKV, CKV, 4096, 512, 2048, 0, 1.0f);
  gemm_kernel<0><<<dim3(4, 32), 256, 0, stream>>>(XB, WCQ, CQ, 4096, 512, 2048, 0, 1.0f);
  gemm_kernel<2><<<dim3(16, 32), 256, 0, stream>>>(CKV, WK, KCAT, 4096, 2048, 512, 192, 1.0f);
  gemm_kernel<2><<<dim3(16, 32), 256, 0, stream>>>(CKV, WV, VH, 4096, 2048, 512, 128, 1.0f);
  gemm_kernel<2><<<dim3(16, 32), 256, 0, stream>>>(CQ, WQ, QCAT, 4096, 2048, 512, 192, SC);
  gemm_kernel<0><<<dim3(8, 32), 256, 0, stream>>>(CQ, WQR, QR, 4096, 1024, 512, 0, 1.0f);
  gemm_kernel<0><<<dim3(1, 32), 256, 0, stream>>>(XB, WKR, KR, 4096, 64, 2048, 0, 1.0f);

  rope_assemble_kernel<<<8192, 256, 0, stream>>>(QR, KR, COS_T, SIN_T, QCAT, KCAT);

  attn_kernel<<<dim3(32, 16, 2), 256, 0, stream>>>(QCAT, KCAT, VH, AOUT);

  gemm_kernel<1><<<dim3(16, 32), 256, 0, stream>>>(AOUT, WO, d_out, 4096, 2048, 2048, 0, 1.0f);
}

// Round 4
// 376.772 us; speedup vs baseline: 2.7876x; 2.7876x over previous
//
#include <hip/hip_runtime.h>

// MLA v3 forward, MI355X/gfx950. Round 4.
// Fix vs rounds 2/3: w_cq transpose called with correct shape [2048,512]
// (was copy-pasted as [512,2048] -> garbage Q path, absmax 0.27).
// - Weights pre-transposed to bf16 [N][K].
// - GEMM: 128x128 tile, BK=64, padded LDS stride 72, reg-staged prefetch.
// - V written pre-transposed [b,h,d,s] by MODE 3 epilogue.
// - Attention: 512-thr blocks (8 waves), QBLK=128, KV tile 64, causal
//   pairing (block p does q-tiles p and 15-p), conflict-free LDS strides.

typedef unsigned short u16;
typedef __attribute__((ext_vector_type(8))) short s16x8;
typedef __attribute__((ext_vector_type(4))) float f32x4;
typedef __attribute__((ext_vector_type(8))) __bf16 bf16x8;
typedef __attribute__((ext_vector_type(4))) u16 u16x4;

#define S_LEN 2048
#define NH 16
#define HD 128
#define DQK 192
#define EMB 2048

__device__ __forceinline__ u16 f2b(float f) {
  unsigned u = __builtin_bit_cast(unsigned, f);
  u += 0x7FFFu + ((u >> 16) & 1u);           // RNE to bf16
  return (u16)(u >> 16);
}
__device__ __forceinline__ float b2f(u16 v) {
  unsigned u = ((unsigned)v) << 16;
  return __builtin_bit_cast(float, u);
}
__device__ __forceinline__ bf16x8 ld_bf8(const u16* p) {
  return __builtin_bit_cast(bf16x8, *(const s16x8*)p);
}

__global__ __launch_bounds__(256) void f2b_kernel(const float* __restrict__ in,
                                                  u16* __restrict__ out, int n4) {
  int i = blockIdx.x * 256 + threadIdx.x;
  if (i >= n4) return;
  f32x4 v = *(const f32x4*)(in + (size_t)i * 4);
  u16x4 o = { f2b(v[0]), f2b(v[1]), f2b(v[2]), f2b(v[3]) };
  *(u16x4*)(out + (size_t)i * 4) = o;
}

// in: f32 [K][N] row-major -> out: bf16 [N][K] row-major. 64x64 tiles.
// Grid must be dim3(N/64, K/64).
__global__ __launch_bounds__(256) void transpose_f2b_kernel(const float* __restrict__ in,
                                                            u16* __restrict__ out,
                                                            int K, int N) {
  __shared__ u16 T[64 * 72];
  const int n0 = blockIdx.x * 64, k0 = blockIdx.y * 64;
  const int t = threadIdx.x;
#pragma unroll
  for (int r = 0; r < 4; ++r) {
    int kl = (t >> 4) + r * 16, nl = (t & 15) * 4;
    f32x4 v = *(const f32x4*)(in + (size_t)(k0 + kl) * N + n0 + nl);
#pragma unroll
    for (int j = 0; j < 4; ++j) T[(nl + j) * 72 + kl] = f2b(v[j]);
  }
  __syncthreads();
#pragma unroll
  for (int r = 0; r < 2; ++r) {
    int chunk = t + r * 256, nr = chunk >> 3, kc = (chunk & 7) * 8;
    *(s16x8*)(out + (size_t)(n0 + nr) * K + k0 + kc) = *(const s16x8*)(&T[nr * 72 + kc]);
  }
}

__global__ __launch_bounds__(256) void rope_table_kernel(float* __restrict__ cosT,
                                                         float* __restrict__ sinT) {
  int id = blockIdx.x * 256 + threadIdx.x;   // S_LEN*32
  int s = id >> 5, i = id & 31;
  float inv = exp2f(-(float)i * (13.287712379549449f / 32.0f));
  float ang = (float)s * inv;
  cosT[id] = cosf(ang);
  sinT[id] = sinf(ang);
}

// C = A[M,K] @ BT[N,K]^T, bf16 in, fp32 accum. 128x128 tile, BK=64.
// LDS row stride 72 (odd granule count -> conflict-light, no swizzle).
// MODE 0: bf16 [M,N]; MODE 1: fp32 [M,N];
// MODE 2: bf16 head-major [b][h][s][ostride], h=col>>7, d=col&127, scaled;
// MODE 3: bf16 V^T head-major [b][h][d][s].
template<int MODE>
__global__ __launch_bounds__(256) void gemm_bt_kernel(const u16* __restrict__ A,
                                                      const u16* __restrict__ BT,
                                                      void* __restrict__ Cout,
                                                      int M, int N, int K,
                                                      int ostride, float scale) {
  __shared__ u16 As[128 * 72];
  __shared__ u16 Bs[128 * 72];
  const int t = threadIdx.x;
  const int lane = t & 63, wid = t >> 6;
  const int wr = (wid >> 1) * 64, wc = (wid & 1) * 64;
  const int bm0 = blockIdx.y * 128, bn0 = blockIdx.x * 128;
  const int lr = lane & 15, lg = lane >> 4;

  s16x8 pa[4], pb[4];
  auto gload = [&](int k0) {
#pragma unroll
    for (int r = 0; r < 4; ++r) {
      int chunk = t + r * 256, row = chunk >> 3, kc = (chunk & 7) * 8;
      pa[r] = *(const s16x8*)(A + (size_t)(bm0 + row) * K + k0 + kc);
      int brow = bn0 + row;
      s16x8 z = {};
      pb[r] = (brow < N) ? *(const s16x8*)(BT + (size_t)brow * K + k0 + kc) : z;
    }
  };
  auto swr = [&]() {
#pragma unroll
    for (int r = 0; r < 4; ++r) {
      int chunk = t + r * 256, row = chunk >> 3, kc = (chunk & 7) * 8;
      *(s16x8*)(&As[row * 72 + kc]) = pa[r];
      *(s16x8*)(&Bs[row * 72 + kc]) = pb[r];
    }
  };

  f32x4 acc[4][4] = {};
  const int nt = K >> 6;
  gload(0);
  swr();
  for (int tk = 0; tk < nt; ++tk) {
    if (tk + 1 < nt) gload((tk + 1) << 6);
    __syncthreads();                            // tile tk writes visible
#pragma unroll
    for (int kk = 0; kk < 2; ++kk) {
      bf16x8 af[4], bfr[4];
      const int kbase = kk * 32 + lg * 8;
#pragma unroll
      for (int m = 0; m < 4; ++m)
        af[m] = ld_bf8(&As[(wr + m * 16 + lr) * 72 + kbase]);
#pragma unroll
      for (int n = 0; n < 4; ++n)
        bfr[n] = ld_bf8(&Bs[(wc + n * 16 + lr) * 72 + kbase]);
#pragma unroll
      for (int m = 0; m < 4; ++m)
#pragma unroll
        for (int n = 0; n < 4; ++n)
          acc[m][n] = __builtin_amdgcn_mfma_f32_16x16x32_bf16(af[m], bfr[n], acc[m][n], 0, 0, 0);
    }
    __syncthreads();                            // all reads of tile tk done
    if (tk + 1 < nt) swr();
  }

  // C/D layout: col = lane&15, row = (lane>>4)*4 + reg
#pragma unroll
  for (int m = 0; m < 4; ++m)
#pragma unroll
    for (int n = 0; n < 4; ++n)
#pragma unroll
      for (int rg = 0; rg < 4; ++rg) {
        int row = bm0 + wr + m * 16 + lg * 4 + rg;
        int col = bn0 + wc + n * 16 + lr;
        if (col >= N) continue;
        float v = acc[m][n][rg] * scale;
        if (MODE == 0) {
          ((u16*)Cout)[(size_t)row * N + col] = f2b(v);
        } else if (MODE == 1) {
          ((float*)Cout)[(size_t)row * N + col] = v;
        } else if (MODE == 2) {
          int bb = row >> 11, s = row & 2047;
          int h = col >> 7, d = col & 127;
          ((u16*)Cout)[((size_t)(bb * NH + h) * S_LEN + s) * (size_t)ostride + d] = f2b(v);
        } else {
          int bb = row >> 11, s = row & 2047;
          int h = col >> 7, d = col & 127;
          ((u16*)Cout)[((size_t)(bb * NH + h) * HD + d) * S_LEN + s] = f2b(v);
        }
      }
}

// Fill rope halves of Qcat/Kcat.
__global__ __launch_bounds__(256) void rope_assemble_kernel(const u16* __restrict__ qr,
                                                            const u16* __restrict__ kr,
                                                            const float* __restrict__ cosT,
                                                            const float* __restrict__ sinT,
                                                            u16* __restrict__ Qcat,
                                                            u16* __restrict__ Kcat) {
  int id = blockIdx.x * 256 + threadIdx.x;   // B*H*S*32 = 2^21
  int i = id & 31;
  int s = (id >> 5) & 2047;
  int h = (id >> 16) & 15;
  int b = id >> 20;
  float c = cosT[(s << 5) + i], sn = sinT[(s << 5) + i];
  const float SC = 0.07216878364870323f;     // 1/sqrt(192)

  size_t qbase = ((size_t)b * S_LEN + s) * 1024 + h * 64 + 2 * i;
  float qe = b2f(qr[qbase]), qo = b2f(qr[qbase + 1]);
  size_t obase = ((size_t)(b * NH + h) * S_LEN + s) * DQK + HD + 2 * i;
  Qcat[obase]     = f2b((qe * c - qo * sn) * SC);
  Qcat[obase + 1] = f2b((qe * sn + qo * c) * SC);

  size_t kbase = ((size_t)b * S_LEN + s) * 64 + 2 * i;
  float ke = b2f(kr[kbase]), ko = b2f(kr[kbase + 1]);
  Kcat[obase]     = f2b(ke * c - ko * sn);
  Kcat[obase + 1] = f2b(ke * sn + ko * c);
}

// Flash attention, causal, paired q-tiles for load balance.
// Q,K: [B][H][S][192] bf16 (Q pre-scaled); VT: [B][H][128][S] bf16.
// Block = 512 thr (8 waves); q-tile = 128 rows (16/wave); kv tile 64.
// Block p handles q-tiles p and 15-p -> uniform 34 kv-tiles per block.
__global__ __launch_bounds__(512, 2) void attn_kernel(const u16* __restrict__ Q,
                                                      const u16* __restrict__ K,
                                                      const u16* __restrict__ VT,
                                                      u16* __restrict__ O) {
  __shared__ u16 Ks[64 * 200];    // [kv][d0..191], stride 200 (400B, odd 16B-group)
  __shared__ u16 Vs[128 * 72];    // [d][kv0..63], stride 72 (144B, odd group)
  __shared__ u16 Ps[8 * 16 * 88]; // per-wave [q][kv], stride 88 (176B)
  const int p = blockIdx.x, h = blockIdx.y, b = blockIdx.z;
  const int t = threadIdx.x, lane = t & 63, wid = t >> 6;
  const int lr = lane & 15, lg = lane >> 4;
  const size_t qk_head = (size_t)(b * NH + h) * S_LEN * DQK;
  const size_t vt_head = (size_t)(b * NH + h) * HD * S_LEN;

  s16x8 kst[3], vst[2];
  auto gload = [&](int kt) {
#pragma unroll
    for (int r = 0; r < 3; ++r) {
      int chunk = t + r * 512, row = chunk / 24, cc = chunk % 24;
      kst[r] = *(const s16x8*)(K + qk_head + (size_t)(kt * 64 + row) * DQK + cc * 8);
    }
#pragma unroll
    for (int r = 0; r < 2; ++r) {
      int chunk = t + r * 512, d = chunk >> 3, cc = chunk & 7;
      vst[r] = *(const s16x8*)(VT + vt_head + (size_t)d * S_LEN + kt * 64 + cc * 8);
    }
  };
  auto swr = [&]() {
#pragma unroll
    for (int r = 0; r < 3; ++r) {
      int chunk = t + r * 512, row = chunk / 24, cc = chunk % 24;
      *(s16x8*)(&Ks[row * 200 + cc * 8]) = kst[r];
    }
#pragma unroll
    for (int r = 0; r < 2; ++r) {
      int chunk = t + r * 512, d = chunk >> 3, cc = chunk & 7;
      *(s16x8*)(&Vs[d * 72 + cc * 8]) = vst[r];
    }
  };

#pragma unroll 1
  for (int half = 0; half < 2; ++half) {
    const int qb = half ? (15 - p) : p;
    const int q0 = qb * 128;

    bf16x8 qa[6];
    {
      const u16* qrow = Q + qk_head + (size_t)(q0 + wid * 16 + lr) * DQK;
#pragma unroll
      for (int ks = 0; ks < 6; ++ks) qa[ks] = ld_bf8(qrow + ks * 32 + lg * 8);
    }

    f32x4 acc_o[8] = {};
    float m_r[4] = { -INFINITY, -INFINITY, -INFINITY, -INFINITY };
    float l_r[4] = { 0.f, 0.f, 0.f, 0.f };

    const int nt = 2 * qb + 2;
    gload(0);
#pragma unroll 1
    for (int kt = 0; kt < nt; ++kt) {
      __syncthreads();                 // all waves done reading previous tile
      swr();                           // stage tile kt
      if (kt + 1 < nt) gload(kt + 1);  // prefetch next
      __syncthreads();                 // tile kt visible

      f32x4 sacc[4];
#pragma unroll
      for (int cb = 0; cb < 4; ++cb) {
        f32x4 sv = {};
#pragma unroll
        for (int ks = 0; ks < 6; ++ks) {
          bf16x8 kb = ld_bf8(&Ks[(cb * 16 + lr) * 200 + ks * 32 + lg * 8]);
          sv = __builtin_amdgcn_mfma_f32_16x16x32_bf16(qa[ks], kb, sv, 0, 0, 0);
        }
        sacc[cb] = sv;
      }

      if (kt >= 2 * qb) {              // diagonal tiles: causal mask
#pragma unroll
        for (int cb = 0; cb < 4; ++cb)
#pragma unroll
          for (int rg = 0; rg < 4; ++rg) {
            int q_g = q0 + wid * 16 + lg * 4 + rg;
            int kv_g = kt * 64 + cb * 16 + lr;
            if (kv_g > q_g) sacc[cb][rg] = -INFINITY;
          }
      }

      float pmax[4];
#pragma unroll
      for (int rg = 0; rg < 4; ++rg)
        pmax[rg] = fmaxf(fmaxf(sacc[0][rg], sacc[1][rg]), fmaxf(sacc[2][rg], sacc[3][rg]));
#pragma unroll
      for (int off = 1; off < 16; off <<= 1)
#pragma unroll
        for (int rg = 0; rg < 4; ++rg)
          pmax[rg] = fmaxf(pmax[rg], __shfl_xor(pmax[rg], off, 64));

      float alpha[4];
#pragma unroll
      for (int rg = 0; rg < 4; ++rg) {
        float mn = fmaxf(m_r[rg], pmax[rg]);
        alpha[rg] = __expf(m_r[rg] - mn);
        m_r[rg] = mn;
        l_r[rg] *= alpha[rg];
      }
#pragma unroll
      for (int vb = 0; vb < 8; ++vb)
#pragma unroll
        for (int rg = 0; rg < 4; ++rg)
          acc_o[vb][rg] *= alpha[rg];

      float psum[4] = { 0.f, 0.f, 0.f, 0.f };
#pragma unroll
      for (int cb = 0; cb < 4; ++cb)
#pragma unroll
        for (int rg = 0; rg < 4; ++rg) {
          float pv = __expf(sacc[cb][rg] - m_r[rg]);
          sacc[cb][rg] = pv;
          psum[rg] += pv;
        }
#pragma unroll
      for (int off = 1; off < 16; off <<= 1)
#pragma unroll
        for (int rg = 0; rg < 4; ++rg)
          psum[rg] += __shfl_xor(psum[rg], off, 64);
#pragma unroll
      for (int rg = 0; rg < 4; ++rg) l_r[rg] += psum[rg];

      // P -> per-wave LDS (same-wave RAW only)
      u16* psw = &Ps[wid * (16 * 88)];
#pragma unroll
      for (int cb = 0; cb < 4; ++cb)
#pragma unroll
        for (int rg = 0; rg < 4; ++rg)
          psw[(lg * 4 + rg) * 88 + cb * 16 + lr] = f2b(sacc[cb][rg]);

      bf16x8 pa[2];
#pragma unroll
      for (int ks = 0; ks < 2; ++ks) pa[ks] = ld_bf8(&psw[lr * 88 + ks * 32 + lg * 8]);
#pragma unroll
      for (int vb = 0; vb < 8; ++vb) {
#pragma unroll
        for (int ks = 0; ks < 2; ++ks) {
          bf16x8 vv = ld_bf8(&Vs[(vb * 16 + lr) * 72 + ks * 32 + lg * 8]);
          acc_o[vb] = __builtin_amdgcn_mfma_f32_16x16x32_bf16(pa[ks], vv, acc_o[vb], 0, 0, 0);
        }
      }
    }

    // epilogue: O[b][s][h*128+d] bf16
#pragma unroll
    for (int vb = 0; vb < 8; ++vb)
#pragma unroll
      for (int rg = 0; rg < 4; ++rg) {
        int s_glob = q0 + wid * 16 + lg * 4 + rg;
        int col = vb * 16 + lr;
        O[((size_t)b * S_LEN + s_glob) * EMB + h * HD + col] = f2b(acc_o[vb][rg] / l_r[rg]);
      }
  }
}

extern "C" void kernel_launch(void* const* d_in, const int* in_sizes, int n_in,
                              void* d_out, int out_size, void* d_ws, size_t ws_size,
                              hipStream_t stream) {
  const float* xf    = (const float*)d_in[0];
  const float* wckvf = (const float*)d_in[1];
  const float* wkf   = (const float*)d_in[2];
  const float* wvf   = (const float*)d_in[3];
  const float* wcqf  = (const float*)d_in[4];
  const float* wqf   = (const float*)d_in[5];
  const float* wqrf  = (const float*)d_in[6];
  const float* wkrf  = (const float*)d_in[7];
  const float* wof   = (const float*)d_in[8];
  (void)in_sizes; (void)n_in; (void)out_size; (void)ws_size;

  u16* ws = (u16*)d_ws;
  size_t off = 0;
  auto alloc = [&](size_t n) -> u16* { u16* p = ws + off; off += n; return p; };
  u16* XB     = alloc(8388608);   // x bf16 [4096,2048]
  u16* WCKV_T = alloc(1048576);   // [512,2048]
  u16* WK_T   = alloc(1048576);   // [2048,512]
  u16* WV_T   = alloc(1048576);   // [2048,512]
  u16* WCQ_T  = alloc(1048576);   // [512,2048]
  u16* WQ_T   = alloc(1048576);   // [2048,512]
  u16* WQR_T  = alloc(524288);    // [1024,512]
  u16* WKR_T  = alloc(131072);    // [64,2048]
  u16* WO_T   = alloc(4194304);   // [2048,2048]
  u16* CKV    = alloc(2097152);   // [4096,512]
  u16* CQ     = alloc(2097152);
  u16* QR     = alloc(4194304);   // [4096,1024]
  u16* KR     = alloc(262144);    // [4096,64]
  u16* QCAT   = alloc(12582912);  // [B,H,S,192]
  u16* KCAT   = alloc(12582912);
  u16* VT     = alloc(8388608);   // [B,H,128,S]
  u16* AOUT   = alloc(8388608);   // [4096,2048]
  float* COS_T = (float*)alloc(131072);
  float* SIN_T = (float*)alloc(131072);

  f2b_kernel<<<8192, 256, 0, stream>>>(xf, XB, 2097152);

  // transpose_f2b(in, out, K, N) with in = [K][N]; grid = dim3(N/64, K/64).
  transpose_f2b_kernel<<<dim3(8, 32),  256, 0, stream>>>(wckvf, WCKV_T, 2048, 512);
  transpose_f2b_kernel<<<dim3(32, 8),  256, 0, stream>>>(wkf,   WK_T,   512, 2048);
  transpose_f2b_kernel<<<dim3(32, 8),  256, 0, stream>>>(wvf,   WV_T,   512, 2048);
  transpose_f2b_kernel<<<dim3(8, 32),  256, 0, stream>>>(wcqf,  WCQ_T,  2048, 512);  // FIXED: w_cq is [2048,512]
  transpose_f2b_kernel<<<dim3(32, 8),  256, 0, stream>>>(wqf,   WQ_T,   512, 2048);
  transpose_f2b_kernel<<<dim3(16, 8),  256, 0, stream>>>(wqrf,  WQR_T,  512, 1024);
  transpose_f2b_kernel<<<dim3(1, 32),  256, 0, stream>>>(wkrf,  WKR_T,  2048, 64);
  transpose_f2b_kernel<<<dim3(32, 32), 256, 0, stream>>>(wof,   WO_T,   2048, 2048);

  rope_table_kernel<<<256, 256, 0, stream>>>(COS_T, SIN_T);

  const float SC = 0.07216878364870323f;  // 1/sqrt(192)
  gemm_bt_kernel<0><<<dim3(4, 32),  256, 0, stream>>>(XB,  WCKV_T, CKV,   4096, 512,  2048, 0,   1.0f);
  gemm_bt_kernel<0><<<dim3(4, 32),  256, 0, stream>>>(XB,  WCQ_T,  CQ,    4096, 512,  2048, 0,   1.0f);
  gemm_bt_kernel<2><<<dim3(16, 32), 256, 0, stream>>>(CKV, WK_T,   KCAT,  4096, 2048, 512,  192, 1.0f);
  gemm_bt_kernel<3><<<dim3(16, 32), 256, 0, stream>>>(CKV, WV_T,   VT,    4096, 2048, 512,  0,   1.0f);
  gemm_bt_kernel<2><<<dim3(16, 32), 256, 0, stream>>>(CQ,  WQ_T,   QCAT,  4096, 2048, 512,  192, SC);
  gemm_bt_kernel<0><<<dim3(8, 32),  256, 0, stream>>>(CQ,  WQR_T,  QR,    4096, 1024, 512,  0,   1.0f);
  gemm_bt_kernel<0><<<dim3(1, 32),  256, 0, stream>>>(XB,  WKR_T,  KR,    4096, 64,   2048, 0,   1.0f);

  rope_assemble_kernel<<<8192, 256, 0, stream>>>(QR, KR, COS_T, SIN_T, QCAT, KCAT);

  attn_kernel<<<dim3(8, 16, 2), 512, 0, stream>>>(QCAT, KCAT, VT, AOUT);

  gemm_bt_kernel<1><<<dim3(16, 32), 256, 0, stream>>>(AOUT, WO_T, d_out, 4096, 2048, 2048, 0, 1.0f);
}

// Round 6
// 371.836 us; speedup vs baseline: 2.8246x; 1.0133x over previous
//
#include <hip/hip_runtime.h>

// MLA v3 forward, MI355X/gfx950. Round 6.
// Fixes vs round 5: (1) GEMM global_load_lds staging covers the FULL
// 128x64 tile (r<4 = 1024 chunks; r<2 left half the LDS uninitialized ->
// absmax 2.9e10); (2) Ps stride back to 88 (16B-aligned ds_read_b128;
// stride 84 was 8B-aligned for odd rows -> undefined reads).

typedef unsigned short u16;
typedef __attribute__((ext_vector_type(8))) short s16x8;
typedef __attribute__((ext_vector_type(4))) float f32x4;
typedef __attribute__((ext_vector_type(8))) __bf16 bf16x8;
typedef __attribute__((ext_vector_type(4))) u16 u16x4;

#define S_LEN 2048
#define NH 16
#define HD 128
#define DQK 192
#define EMB 2048

#define GLOAD_LDS16(g, l)                                                      \
  __builtin_amdgcn_global_load_lds(                                            \
      (const __attribute__((address_space(1))) unsigned int*)(g),              \
      (__attribute__((address_space(3))) unsigned int*)(l), 16, 0, 0)

__device__ __forceinline__ u16 f2b(float f) {
  unsigned u = __builtin_bit_cast(unsigned, f);
  u += 0x7FFFu + ((u >> 16) & 1u);           // RNE to bf16
  return (u16)(u >> 16);
}
__device__ __forceinline__ float b2f(u16 v) {
  unsigned u = ((unsigned)v) << 16;
  return __builtin_bit_cast(float, u);
}
__device__ __forceinline__ bf16x8 ld_bf8(const u16* p) {
  return __builtin_bit_cast(bf16x8, *(const s16x8*)p);
}

__global__ __launch_bounds__(256) void f2b_kernel(const float* __restrict__ in,
                                                  u16* __restrict__ out, int n4) {
  int i = blockIdx.x * 256 + threadIdx.x;
  if (i >= n4) return;
  f32x4 v = *(const f32x4*)(in + (size_t)i * 4);
  u16x4 o = { f2b(v[0]), f2b(v[1]), f2b(v[2]), f2b(v[3]) };
  *(u16x4*)(out + (size_t)i * 4) = o;
}

// in: f32 [K][N] row-major -> out: bf16 [N][K] row-major. 64x64 tiles.
// Grid must be dim3(N/64, K/64).
__global__ __launch_bounds__(256) void transpose_f2b_kernel(const float* __restrict__ in,
                                                            u16* __restrict__ out,
                                                            int K, int N) {
  __shared__ u16 T[64 * 72];
  const int n0 = blockIdx.x * 64, k0 = blockIdx.y * 64;
  const int t = threadIdx.x;
#pragma unroll
  for (int r = 0; r < 4; ++r) {
    int kl = (t >> 4) + r * 16, nl = (t & 15) * 4;
    f32x4 v = *(const f32x4*)(in + (size_t)(k0 + kl) * N + n0 + nl);
#pragma unroll
    for (int j = 0; j < 4; ++j) T[(nl + j) * 72 + kl] = f2b(v[j]);
  }
  __syncthreads();
#pragma unroll
  for (int r = 0; r < 2; ++r) {
    int chunk = t + r * 256, nr = chunk >> 3, kc = (chunk & 7) * 8;
    *(s16x8*)(out + (size_t)(n0 + nr) * K + k0 + kc) = *(const s16x8*)(&T[nr * 72 + kc]);
  }
}

__global__ __launch_bounds__(256) void rope_table_kernel(float* __restrict__ cosT,
                                                         float* __restrict__ sinT) {
  int id = blockIdx.x * 256 + threadIdx.x;   // S_LEN*32
  int s = id >> 5, i = id & 31;
  float inv = exp2f(-(float)i * (13.287712379549449f / 32.0f));
  float ang = (float)s * inv;
  cosT[id] = cosf(ang);
  sinT[id] = sinf(ang);
}

// C = A[M,K] @ BT[N,K]^T, bf16 in, fp32 accum. 128x128 tile, BK=64.
// Staging: global_load_lds 16B, linear LDS, source pre-swizzled
// (kc_g = kc_s ^ ((row&7)<<3)); ds_read applies the same XOR.
// MODE 0: bf16 [M,N]; MODE 1: fp32 [M,N];
// MODE 2: bf16 head-major [b][h][s][ostride], h=col>>7, d=col&127, scaled;
// MODE 3: bf16 V^T head-major [b][h][d][s].
template<int MODE>
__global__ __launch_bounds__(256) void gemm_bt_kernel(const u16* __restrict__ A,
                                                      const u16* __restrict__ BT,
                                                      void* __restrict__ Cout,
                                                      int M, int N, int K,
                                                      int ostride, float scale) {
  __shared__ __align__(16) u16 As[128 * 64];
  __shared__ __align__(16) u16 Bs[128 * 64];
  const int t = threadIdx.x;
  const int lane = t & 63, wid = t >> 6;
  const int wr = (wid >> 1) * 64, wc = (wid & 1) * 64;
  const int bm0 = blockIdx.y * 128, bn0 = blockIdx.x * 128;
  const int lr = lane & 15, lg = lane >> 4;

  f32x4 acc[4][4] = {};
  const int nt = K >> 6;
  for (int tk = 0; tk < nt; ++tk) {
    const int k0 = tk << 6;
    __syncthreads();                         // prior reads done; safe to overwrite
#pragma unroll
    for (int r = 0; r < 4; ++r) {            // stage A: 128x64 = 1024 chunks of 16B
      int chunk = t + r * 256;
      int row = chunk >> 3, kcs = (chunk & 7) * 8;
      int kcg = kcs ^ ((row & 7) << 3);      // inverse swizzle on SOURCE
      GLOAD_LDS16(A + (size_t)(bm0 + row) * K + k0 + kcg, &As[chunk * 8]);
    }
#pragma unroll
    for (int r = 0; r < 4; ++r) {            // stage B
      int chunk = t + r * 256;
      int row = chunk >> 3, kcs = (chunk & 7) * 8;
      int kcg = kcs ^ ((row & 7) << 3);
      GLOAD_LDS16(BT + (size_t)(bn0 + row) * K + k0 + kcg, &Bs[chunk * 8]);
    }
    __syncthreads();                         // vmcnt drained; tile visible
#pragma unroll
    for (int kk = 0; kk < 2; ++kk) {
      bf16x8 af[4], bfr[4];
      const int kbase = kk * 32 + lg * 8;
#pragma unroll
      for (int m = 0; m < 4; ++m) {
        int row = wr + m * 16 + lr;
        af[m] = ld_bf8(&As[row * 64 + (kbase ^ ((row & 7) << 3))]);
      }
#pragma unroll
      for (int n = 0; n < 4; ++n) {
        int row = wc + n * 16 + lr;
        bfr[n] = ld_bf8(&Bs[row * 64 + (kbase ^ ((row & 7) << 3))]);
      }
#pragma unroll
      for (int m = 0; m < 4; ++m)
#pragma unroll
        for (int n = 0; n < 4; ++n)
          acc[m][n] = __builtin_amdgcn_mfma_f32_16x16x32_bf16(af[m], bfr[n], acc[m][n], 0, 0, 0);
    }
  }

  // C/D layout: col = lane&15, row = (lane>>4)*4 + reg
#pragma unroll
  for (int m = 0; m < 4; ++m)
#pragma unroll
    for (int n = 0; n < 4; ++n)
#pragma unroll
      for (int rg = 0; rg < 4; ++rg) {
        int row = bm0 + wr + m * 16 + lg * 4 + rg;
        int col = bn0 + wc + n * 16 + lr;
        if (col >= N) continue;
        float v = acc[m][n][rg] * scale;
        if (MODE == 0) {
          ((u16*)Cout)[(size_t)row * N + col] = f2b(v);
        } else if (MODE == 1) {
          ((float*)Cout)[(size_t)row * N + col] = v;
        } else if (MODE == 2) {
          int bb = row >> 11, s = row & 2047;
          int h = col >> 7, d = col & 127;
          ((u16*)Cout)[((size_t)(bb * NH + h) * S_LEN + s) * (size_t)ostride + d] = f2b(v);
        } else {
          int bb = row >> 11, s = row & 2047;
          int h = col >> 7, d = col & 127;
          ((u16*)Cout)[((size_t)(bb * NH + h) * HD + d) * S_LEN + s] = f2b(v);
        }
      }
}

// Fill rope halves of Qcat/Kcat.
__global__ __launch_bounds__(256) void rope_assemble_kernel(const u16* __restrict__ qr,
                                                            const u16* __restrict__ kr,
                                                            const float* __restrict__ cosT,
                                                            const float* __restrict__ sinT,
                                                            u16* __restrict__ Qcat,
                                                            u16* __restrict__ Kcat) {
  int id = blockIdx.x * 256 + threadIdx.x;   // B*H*S*32 = 2^21
  int i = id & 31;
  int s = (id >> 5) & 2047;
  int h = (id >> 16) & 15;
  int b = id >> 20;
  float c = cosT[(s << 5) + i], sn = sinT[(s << 5) + i];
  const float SC = 0.07216878364870323f;     // 1/sqrt(192)

  size_t qbase = ((size_t)b * S_LEN + s) * 1024 + h * 64 + 2 * i;
  float qe = b2f(qr[qbase]), qo = b2f(qr[qbase + 1]);
  size_t obase = ((size_t)(b * NH + h) * S_LEN + s) * DQK + HD + 2 * i;
  Qcat[obase]     = f2b((qe * c - qo * sn) * SC);
  Qcat[obase + 1] = f2b((qe * sn + qo * c) * SC);

  size_t kbase = ((size_t)b * S_LEN + s) * 64 + 2 * i;
  float ke = b2f(kr[kbase]), ko = b2f(kr[kbase + 1]);
  Kcat[obase]     = f2b(ke * c - ko * sn);
  Kcat[obase + 1] = f2b(ke * sn + ko * c);
}

// Flash attention, causal, paired q-tiles.
// Q,K: [B][H][S][192] bf16 (Q pre-scaled); VT: [B][H][128][S] bf16.
// Block = 256 thr (4 waves); q-tile = 64 rows (16/wave); kv tile 64.
// Block p handles q-tiles p and 31-p -> uniform 33 kv-tiles; grid 512
// blocks = 2 blocks/CU so independent blocks overlap barrier stalls.
__global__ __launch_bounds__(256, 2) void attn_kernel(const u16* __restrict__ Q,
                                                      const u16* __restrict__ K,
                                                      const u16* __restrict__ VT,
                                                      u16* __restrict__ O) {
  __shared__ u16 Ks[64 * 200];    // [kv][d0..191], stride 200 (400B)
  __shared__ u16 Vs[128 * 72];    // [d][kv0..63], stride 72 (144B)
  __shared__ u16 Ps[4 * 16 * 88]; // per-wave [q][kv], stride 88 (176B, 16B-mult)
  const int p = blockIdx.x, h = blockIdx.y, b = blockIdx.z;
  const int t = threadIdx.x, lane = t & 63, wid = t >> 6;
  const int lr = lane & 15, lg = lane >> 4;
  const size_t qk_head = (size_t)(b * NH + h) * S_LEN * DQK;
  const size_t vt_head = (size_t)(b * NH + h) * HD * S_LEN;

  s16x8 kst[6], vst[4];
  auto gload = [&](int kt) {
#pragma unroll
    for (int r = 0; r < 6; ++r) {
      int chunk = t + r * 256, row = chunk / 24, cc = chunk % 24;
      kst[r] = *(const s16x8*)(K + qk_head + (size_t)(kt * 64 + row) * DQK + cc * 8);
    }
#pragma unroll
    for (int r = 0; r < 4; ++r) {
      int chunk = t + r * 256, d = chunk >> 3, cc = chunk & 7;
      vst[r] = *(const s16x8*)(VT + vt_head + (size_t)d * S_LEN + kt * 64 + cc * 8);
    }
  };
  auto swr = [&]() {
#pragma unroll
    for (int r = 0; r < 6; ++r) {
      int chunk = t + r * 256, row = chunk / 24, cc = chunk % 24;
      *(s16x8*)(&Ks[row * 200 + cc * 8]) = kst[r];
    }
#pragma unroll
    for (int r = 0; r < 4; ++r) {
      int chunk = t + r * 256, d = chunk >> 3, cc = chunk & 7;
      *(s16x8*)(&Vs[d * 72 + cc * 8]) = vst[r];
    }
  };

#pragma unroll 1
  for (int half = 0; half < 2; ++half) {
    const int qb = half ? (31 - p) : p;
    const int q0 = qb * 64;

    bf16x8 qa[6];
    {
      const u16* qrow = Q + qk_head + (size_t)(q0 + wid * 16 + lr) * DQK;
#pragma unroll
      for (int ks = 0; ks < 6; ++ks) qa[ks] = ld_bf8(qrow + ks * 32 + lg * 8);
    }

    f32x4 acc_o[8] = {};
    float m_r[4] = { -INFINITY, -INFINITY, -INFINITY, -INFINITY };
    float l_r[4] = { 0.f, 0.f, 0.f, 0.f };

    const int nt = qb + 1;
    gload(0);
#pragma unroll 1
    for (int kt = 0; kt < nt; ++kt) {
      __syncthreads();                 // all waves done reading previous tile
      swr();                           // stage tile kt
      if (kt + 1 < nt) gload(kt + 1);  // prefetch next
      __syncthreads();                 // tile kt visible

      f32x4 sacc[4];
#pragma unroll
      for (int cb = 0; cb < 4; ++cb) {
        f32x4 sv = {};
#pragma unroll
        for (int ks = 0; ks < 6; ++ks) {
          bf16x8 kb = ld_bf8(&Ks[(cb * 16 + lr) * 200 + ks * 32 + lg * 8]);
          sv = __builtin_amdgcn_mfma_f32_16x16x32_bf16(qa[ks], kb, sv, 0, 0, 0);
        }
        sacc[cb] = sv;
      }

      if (kt == qb) {                  // diagonal tile: causal mask
#pragma unroll
        for (int cb = 0; cb < 4; ++cb)
#pragma unroll
          for (int rg = 0; rg < 4; ++rg) {
            int q_g = q0 + wid * 16 + lg * 4 + rg;
            int kv_g = kt * 64 + cb * 16 + lr;
            if (kv_g > q_g) sacc[cb][rg] = -INFINITY;
          }
      }

      float pmax[4];
#pragma unroll
      for (int rg = 0; rg < 4; ++rg)
        pmax[rg] = fmaxf(fmaxf(sacc[0][rg], sacc[1][rg]), fmaxf(sacc[2][rg], sacc[3][rg]));
#pragma unroll
      for (int off = 1; off < 16; off <<= 1)
#pragma unroll
        for (int rg = 0; rg < 4; ++rg)
          pmax[rg] = fmaxf(pmax[rg], __shfl_xor(pmax[rg], off, 64));

      float alpha[4];
#pragma unroll
      for (int rg = 0; rg < 4; ++rg) {
        float mn = fmaxf(m_r[rg], pmax[rg]);
        alpha[rg] = __expf(m_r[rg] - mn);
        m_r[rg] = mn;
        l_r[rg] *= alpha[rg];
      }
#pragma unroll
      for (int vb = 0; vb < 8; ++vb)
#pragma unroll
        for (int rg = 0; rg < 4; ++rg)
          acc_o[vb][rg] *= alpha[rg];

      float psum[4] = { 0.f, 0.f, 0.f, 0.f };
#pragma unroll
      for (int cb = 0; cb < 4; ++cb)
#pragma unroll
        for (int rg = 0; rg < 4; ++rg) {
          float pv = __expf(sacc[cb][rg] - m_r[rg]);
          sacc[cb][rg] = pv;
          psum[rg] += pv;
        }
#pragma unroll
      for (int off = 1; off < 16; off <<= 1)
#pragma unroll
        for (int rg = 0; rg < 4; ++rg)
          psum[rg] += __shfl_xor(psum[rg], off, 64);
#pragma unroll
      for (int rg = 0; rg < 4; ++rg) l_r[rg] += psum[rg];

      // P -> per-wave LDS (same-wave RAW only)
      u16* psw = &Ps[wid * (16 * 88)];
#pragma unroll
      for (int cb = 0; cb < 4; ++cb)
#pragma unroll
        for (int rg = 0; rg < 4; ++rg)
          psw[(lg * 4 + rg) * 88 + cb * 16 + lr] = f2b(sacc[cb][rg]);

      bf16x8 pa[2];
#pragma unroll
      for (int ks = 0; ks < 2; ++ks) pa[ks] = ld_bf8(&psw[lr * 88 + ks * 32 + lg * 8]);
#pragma unroll
      for (int vb = 0; vb < 8; ++vb) {
#pragma unroll
        for (int ks = 0; ks < 2; ++ks) {
          bf16x8 vv = ld_bf8(&Vs[(vb * 16 + lr) * 72 + ks * 32 + lg * 8]);
          acc_o[vb] = __builtin_amdgcn_mfma_f32_16x16x32_bf16(pa[ks], vv, acc_o[vb], 0, 0, 0);
        }
      }
    }

    // epilogue: O[b][s][h*128+d] bf16
#pragma unroll
    for (int vb = 0; vb < 8; ++vb)
#pragma unroll
      for (int rg = 0; rg < 4; ++rg) {
        int s_glob = q0 + wid * 16 + lg * 4 + rg;
        int col = vb * 16 + lr;
        O[((size_t)b * S_LEN + s_glob) * EMB + h * HD + col] = f2b(acc_o[vb][rg] / l_r[rg]);
      }
  }
}

extern "C" void kernel_launch(void* const* d_in, const int* in_sizes, int n_in,
                              void* d_out, int out_size, void* d_ws, size_t ws_size,
                              hipStream_t stream) {
  const float* xf    = (const float*)d_in[0];
  const float* wckvf = (const float*)d_in[1];
  const float* wkf   = (const float*)d_in[2];
  const float* wvf   = (const float*)d_in[3];
  const float* wcqf  = (const float*)d_in[4];
  const float* wqf   = (const float*)d_in[5];
  const float* wqrf  = (const float*)d_in[6];
  const float* wkrf  = (const float*)d_in[7];
  const float* wof   = (const float*)d_in[8];
  (void)in_sizes; (void)n_in; (void)out_size; (void)ws_size;

  u16* ws = (u16*)d_ws;
  size_t off = 0;
  auto alloc = [&](size_t n) -> u16* { u16* p = ws + off; off += n; return p; };
  u16* XB     = alloc(8388608);   // x bf16 [4096,2048]
  u16* WCKV_T = alloc(1048576);   // [512,2048]
  u16* WK_T   = alloc(1048576);   // [2048,512]
  u16* WV_T   = alloc(1048576);   // [2048,512]
  u16* WCQ_T  = alloc(1048576);   // [512,2048]
  u16* WQ_T   = alloc(1048576);   // [2048,512]
  u16* WQR_T  = alloc(524288);    // [1024,512]
  u16* WKR_T  = alloc(131072);    // [64,2048]
  u16* WO_T   = alloc(4194304);   // [2048,2048]
  u16* CKV    = alloc(2097152);   // [4096,512]
  u16* CQ     = alloc(2097152);
  u16* QR     = alloc(4194304);   // [4096,1024]
  u16* KR     = alloc(262144);    // [4096,64]
  u16* QCAT   = alloc(12582912);  // [B,H,S,192]
  u16* KCAT   = alloc(12582912);
  u16* VT     = alloc(8388608);   // [B,H,128,S]
  u16* AOUT   = alloc(8388608);   // [4096,2048]
  float* COS_T = (float*)alloc(131072);
  float* SIN_T = (float*)alloc(131072);

  f2b_kernel<<<8192, 256, 0, stream>>>(xf, XB, 2097152);

  // transpose_f2b(in, out, K, N) with in = [K][N]; grid = dim3(N/64, K/64).
  transpose_f2b_kernel<<<dim3(8, 32),  256, 0, stream>>>(wckvf, WCKV_T, 2048, 512);
  transpose_f2b_kernel<<<dim3(32, 8),  256, 0, stream>>>(wkf,   WK_T,   512, 2048);
  transpose_f2b_kernel<<<dim3(32, 8),  256, 0, stream>>>(wvf,   WV_T,   512, 2048);
  transpose_f2b_kernel<<<dim3(8, 32),  256, 0, stream>>>(wcqf,  WCQ_T,  2048, 512);
  transpose_f2b_kernel<<<dim3(32, 8),  256, 0, stream>>>(wqf,   WQ_T,   512, 2048);
  transpose_f2b_kernel<<<dim3(16, 8),  256, 0, stream>>>(wqrf,  WQR_T,  512, 1024);
  transpose_f2b_kernel<<<dim3(1, 32),  256, 0, stream>>>(wkrf,  WKR_T,  2048, 64);
  transpose_f2b_kernel<<<dim3(32, 32), 256, 0, stream>>>(wof,   WO_T,   2048, 2048);

  rope_table_kernel<<<256, 256, 0, stream>>>(COS_T, SIN_T);

  const float SC = 0.07216878364870323f;  // 1/sqrt(192)
  gemm_bt_kernel<0><<<dim3(4, 32),  256, 0, stream>>>(XB,  WCKV_T, CKV,   4096, 512,  2048, 0,   1.0f);
  gemm_bt_kernel<0><<<dim3(4, 32),  256, 0, stream>>>(XB,  WCQ_T,  CQ,    4096, 512,  2048, 0,   1.0f);
  gemm_bt_kernel<2><<<dim3(16, 32), 256, 0, stream>>>(CKV, WK_T,   KCAT,  4096, 2048, 512,  192, 1.0f);
  gemm_bt_kernel<3><<<dim3(16, 32), 256, 0, stream>>>(CKV, WV_T,   VT,    4096, 2048, 512,  0,   1.0f);
  gemm_bt_kernel<2><<<dim3(16, 32), 256, 0, stream>>>(CQ,  WQ_T,   QCAT,  4096, 2048, 512,  192, SC);
  gemm_bt_kernel<0><<<dim3(8, 32),  256, 0, stream>>>(CQ,  WQR_T,  QR,    4096, 1024, 512,  0,   1.0f);
  gemm_bt_kernel<0><<<dim3(1, 32),  256, 0, stream>>>(XB,  WKR_T,  KR,    4096, 64,   2048, 0,   1.0f);

  rope_assemble_kernel<<<8192, 256, 0, stream>>>(QR, KR, COS_T, SIN_T, QCAT, KCAT);

  attn_kernel<<<dim3(16, 16, 2), 256, 0, stream>>>(QCAT, KCAT, VT, AOUT);

  gemm_bt_kernel<1><<<dim3(16, 32), 256, 0, stream>>>(AOUT, WO_T, d_out, 4096, 2048, 2048, 0, 1.0f);
}

// Round 7
// 364.849 us; speedup vs baseline: 2.8787x; 1.0192x over previous
//
#include <hip/hip_runtime.h>

// MLA v3 forward, MI355X/gfx950. Round 7.
// - GEMM: LDS double-buffer, 1 barrier/iter (stage(t+1) issued before
//   compute(t); next barrier drains vmcnt) -> stage hides under compute.
// - Attention: QBLK=128 via 4 waves x 32 q-rows (2 m-frags per wave) so
//   every K/V LDS fragment read feeds 2 MFMAs; paired q-tiles p & 15-p.

typedef unsigned short u16;
typedef __attribute__((ext_vector_type(8))) short s16x8;
typedef __attribute__((ext_vector_type(4))) float f32x4;
typedef __attribute__((ext_vector_type(8))) __bf16 bf16x8;
typedef __attribute__((ext_vector_type(4))) u16 u16x4;

#define S_LEN 2048
#define NH 16
#define HD 128
#define DQK 192
#define EMB 2048

#define GLOAD_LDS16(g, l)                                                      \
  __builtin_amdgcn_global_load_lds(                                            \
      (const __attribute__((address_space(1))) unsigned int*)(g),              \
      (__attribute__((address_space(3))) unsigned int*)(l), 16, 0, 0)

__device__ __forceinline__ u16 f2b(float f) {
  unsigned u = __builtin_bit_cast(unsigned, f);
  u += 0x7FFFu + ((u >> 16) & 1u);           // RNE to bf16
  return (u16)(u >> 16);
}
__device__ __forceinline__ float b2f(u16 v) {
  unsigned u = ((unsigned)v) << 16;
  return __builtin_bit_cast(float, u);
}
__device__ __forceinline__ bf16x8 ld_bf8(const u16* p) {
  return __builtin_bit_cast(bf16x8, *(const s16x8*)p);
}

__global__ __launch_bounds__(256) void f2b_kernel(const float* __restrict__ in,
                                                  u16* __restrict__ out, int n4) {
  int i = blockIdx.x * 256 + threadIdx.x;
  if (i >= n4) return;
  f32x4 v = *(const f32x4*)(in + (size_t)i * 4);
  u16x4 o = { f2b(v[0]), f2b(v[1]), f2b(v[2]), f2b(v[3]) };
  *(u16x4*)(out + (size_t)i * 4) = o;
}

// in: f32 [K][N] row-major -> out: bf16 [N][K] row-major. 64x64 tiles.
// Grid must be dim3(N/64, K/64).
__global__ __launch_bounds__(256) void transpose_f2b_kernel(const float* __restrict__ in,
                                                            u16* __restrict__ out,
                                                            int K, int N) {
  __shared__ u16 T[64 * 72];
  const int n0 = blockIdx.x * 64, k0 = blockIdx.y * 64;
  const int t = threadIdx.x;
#pragma unroll
  for (int r = 0; r < 4; ++r) {
    int kl = (t >> 4) + r * 16, nl = (t & 15) * 4;
    f32x4 v = *(const f32x4*)(in + (size_t)(k0 + kl) * N + n0 + nl);
#pragma unroll
    for (int j = 0; j < 4; ++j) T[(nl + j) * 72 + kl] = f2b(v[j]);
  }
  __syncthreads();
#pragma unroll
  for (int r = 0; r < 2; ++r) {
    int chunk = t + r * 256, nr = chunk >> 3, kc = (chunk & 7) * 8;
    *(s16x8*)(out + (size_t)(n0 + nr) * K + k0 + kc) = *(const s16x8*)(&T[nr * 72 + kc]);
  }
}

__global__ __launch_bounds__(256) void rope_table_kernel(float* __restrict__ cosT,
                                                         float* __restrict__ sinT) {
  int id = blockIdx.x * 256 + threadIdx.x;   // S_LEN*32
  int s = id >> 5, i = id & 31;
  float inv = exp2f(-(float)i * (13.287712379549449f / 32.0f));
  float ang = (float)s * inv;
  cosT[id] = cosf(ang);
  sinT[id] = sinf(ang);
}

// C = A[M,K] @ BT[N,K]^T, bf16 in, fp32 accum. 128x128 tile, BK=64.
// LDS double-buffer: barrier; stage(t+1 -> buf^1); compute(buf).
// Staging: global_load_lds 16B, linear LDS dest, source pre-swizzled
// (kc_g = kc_s ^ ((row&7)<<3)); ds_read applies the same XOR.
// MODE 0: bf16 [M,N]; MODE 1: fp32 [M,N];
// MODE 2: bf16 head-major [b][h][s][ostride], h=col>>7, d=col&127, scaled;
// MODE 3: bf16 V^T head-major [b][h][d][s].
template<int MODE>
__global__ __launch_bounds__(256) void gemm_bt_kernel(const u16* __restrict__ A,
                                                      const u16* __restrict__ BT,
                                                      void* __restrict__ Cout,
                                                      int M, int N, int K,
                                                      int ostride, float scale) {
  __shared__ __align__(16) u16 As[2][128 * 64];
  __shared__ __align__(16) u16 Bs[2][128 * 64];
  const int t = threadIdx.x;
  const int lane = t & 63, wid = t >> 6;
  const int wr = (wid >> 1) * 64, wc = (wid & 1) * 64;
  const int bm0 = blockIdx.y * 128, bn0 = blockIdx.x * 128;
  const int lr = lane & 15, lg = lane >> 4;

  auto stage = [&](int k0, int buf) {
#pragma unroll
    for (int r = 0; r < 4; ++r) {            // 1024 chunks of 16B each for A and B
      int chunk = t + r * 256;
      int row = chunk >> 3, kcs = (chunk & 7) * 8;
      int kcg = kcs ^ ((row & 7) << 3);      // inverse swizzle on SOURCE
      GLOAD_LDS16(A + (size_t)(bm0 + row) * K + k0 + kcg, &As[buf][chunk * 8]);
      GLOAD_LDS16(BT + (size_t)(bn0 + row) * K + k0 + kcg, &Bs[buf][chunk * 8]);
    }
  };

  f32x4 acc[4][4] = {};
  const int nt = K >> 6;
  stage(0, 0);
  for (int tk = 0; tk < nt; ++tk) {
    const int cur = tk & 1;
    __syncthreads();                         // stage(tk) complete; compute(tk-1) done
    if (tk + 1 < nt) stage((tk + 1) << 6, cur ^ 1);   // hides under compute(tk)
#pragma unroll
    for (int kk = 0; kk < 2; ++kk) {
      bf16x8 af[4], bfr[4];
      const int kbase = kk * 32 + lg * 8;
#pragma unroll
      for (int m = 0; m < 4; ++m) {
        int row = wr + m * 16 + lr;
        af[m] = ld_bf8(&As[cur][row * 64 + (kbase ^ ((row & 7) << 3))]);
      }
#pragma unroll
      for (int n = 0; n < 4; ++n) {
        int row = wc + n * 16 + lr;
        bfr[n] = ld_bf8(&Bs[cur][row * 64 + (kbase ^ ((row & 7) << 3))]);
      }
#pragma unroll
      for (int m = 0; m < 4; ++m)
#pragma unroll
        for (int n = 0; n < 4; ++n)
          acc[m][n] = __builtin_amdgcn_mfma_f32_16x16x32_bf16(af[m], bfr[n], acc[m][n], 0, 0, 0);
    }
  }

  // C/D layout: col = lane&15, row = (lane>>4)*4 + reg
#pragma unroll
  for (int m = 0; m < 4; ++m)
#pragma unroll
    for (int n = 0; n < 4; ++n)
#pragma unroll
      for (int rg = 0; rg < 4; ++rg) {
        int row = bm0 + wr + m * 16 + lg * 4 + rg;
        int col = bn0 + wc + n * 16 + lr;
        if (col >= N) continue;
        float v = acc[m][n][rg] * scale;
        if (MODE == 0) {
          ((u16*)Cout)[(size_t)row * N + col] = f2b(v);
        } else if (MODE == 1) {
          ((float*)Cout)[(size_t)row * N + col] = v;
        } else if (MODE == 2) {
          int bb = row >> 11, s = row & 2047;
          int h = col >> 7, d = col & 127;
          ((u16*)Cout)[((size_t)(bb * NH + h) * S_LEN + s) * (size_t)ostride + d] = f2b(v);
        } else {
          int bb = row >> 11, s = row & 2047;
          int h = col >> 7, d = col & 127;
          ((u16*)Cout)[((size_t)(bb * NH + h) * HD + d) * S_LEN + s] = f2b(v);
        }
      }
}

// Fill rope halves of Qcat/Kcat.
__global__ __launch_bounds__(256) void rope_assemble_kernel(const u16* __restrict__ qr,
                                                            const u16* __restrict__ kr,
                                                            const float* __restrict__ cosT,
                                                            const float* __restrict__ sinT,
                                                            u16* __restrict__ Qcat,
                                                            u16* __restrict__ Kcat) {
  int id = blockIdx.x * 256 + threadIdx.x;   // B*H*S*32 = 2^21
  int i = id & 31;
  int s = (id >> 5) & 2047;
  int h = (id >> 16) & 15;
  int b = id >> 20;
  float c = cosT[(s << 5) + i], sn = sinT[(s << 5) + i];
  const float SC = 0.07216878364870323f;     // 1/sqrt(192)

  size_t qbase = ((size_t)b * S_LEN + s) * 1024 + h * 64 + 2 * i;
  float qe = b2f(qr[qbase]), qo = b2f(qr[qbase + 1]);
  size_t obase = ((size_t)(b * NH + h) * S_LEN + s) * DQK + HD + 2 * i;
  Qcat[obase]     = f2b((qe * c - qo * sn) * SC);
  Qcat[obase + 1] = f2b((qe * sn + qo * c) * SC);

  size_t kbase = ((size_t)b * S_LEN + s) * 64 + 2 * i;
  float ke = b2f(kr[kbase]), ko = b2f(kr[kbase + 1]);
  Kcat[obase]     = f2b(ke * c - ko * sn);
  Kcat[obase + 1] = f2b(ke * sn + ko * c);
}

// Flash attention, causal, paired q-tiles.
// Q,K: [B][H][S][192] bf16 (Q pre-scaled); VT: [B][H][128][S] bf16.
// Block = 256 thr (4 waves); q-tile = 128 rows (32/wave via 2 m-frags);
// kv tile 64. Block p handles q-tiles p and 15-p -> uniform 34 kv-tiles.
// Each K/V LDS fragment read feeds 2 MFMAs (halves LDS-read per q-row).
__global__ __launch_bounds__(256) void attn_kernel(const u16* __restrict__ Q,
                                                   const u16* __restrict__ K,
                                                   const u16* __restrict__ VT,
                                                   u16* __restrict__ O) {
  __shared__ u16 Ks[64 * 200];    // [kv][d0..191], stride 200 (400B)
  __shared__ u16 Vs[128 * 72];    // [d][kv0..63], stride 72 (144B)
  __shared__ u16 Ps[4 * 32 * 88]; // per-wave [q0..31][kv], stride 88 (176B)
  const int p = blockIdx.x, h = blockIdx.y, b = blockIdx.z;
  const int t = threadIdx.x, lane = t & 63, wid = t >> 6;
  const int lr = lane & 15, lg = lane >> 4;
  const size_t qk_head = (size_t)(b * NH + h) * S_LEN * DQK;
  const size_t vt_head = (size_t)(b * NH + h) * HD * S_LEN;

  s16x8 kst[6], vst[4];
  auto gload = [&](int kt) {
#pragma unroll
    for (int r = 0; r < 6; ++r) {
      int chunk = t + r * 256, row = chunk / 24, cc = chunk % 24;
      kst[r] = *(const s16x8*)(K + qk_head + (size_t)(kt * 64 + row) * DQK + cc * 8);
    }
#pragma unroll
    for (int r = 0; r < 4; ++r) {
      int chunk = t + r * 256, d = chunk >> 3, cc = chunk & 7;
      vst[r] = *(const s16x8*)(VT + vt_head + (size_t)d * S_LEN + kt * 64 + cc * 8);
    }
  };
  auto swr = [&]() {
#pragma unroll
    for (int r = 0; r < 6; ++r) {
      int chunk = t + r * 256, row = chunk / 24, cc = chunk % 24;
      *(s16x8*)(&Ks[row * 200 + cc * 8]) = kst[r];
    }
#pragma unroll
    for (int r = 0; r < 4; ++r) {
      int chunk = t + r * 256, d = chunk >> 3, cc = chunk & 7;
      *(s16x8*)(&Vs[d * 72 + cc * 8]) = vst[r];
    }
  };

#pragma unroll 1
  for (int half = 0; half < 2; ++half) {
    const int qb = half ? (15 - p) : p;
    const int q0 = qb * 128;

    bf16x8 qa[2][6];
#pragma unroll
    for (int m = 0; m < 2; ++m) {
      const u16* qrow = Q + qk_head + (size_t)(q0 + wid * 32 + m * 16 + lr) * DQK;
#pragma unroll
      for (int ks = 0; ks < 6; ++ks) qa[m][ks] = ld_bf8(qrow + ks * 32 + lg * 8);
    }

    f32x4 acc_o[2][8] = {};
    float m_r[2][4], l_r[2][4];
#pragma unroll
    for (int m = 0; m < 2; ++m)
#pragma unroll
      for (int rg = 0; rg < 4; ++rg) { m_r[m][rg] = -INFINITY; l_r[m][rg] = 0.f; }

    const int nt = 2 * qb + 2;
    gload(0);
#pragma unroll 1
    for (int kt = 0; kt < nt; ++kt) {
      __syncthreads();                 // all waves done reading previous tile
      swr();                           // stage tile kt (vmcnt wait on kst/vst)
      if (kt + 1 < nt) gload(kt + 1);  // prefetch next (hides under compute)
      __syncthreads();                 // tile kt visible

      // S = Q K^T for both m-frags; each kb read feeds 2 MFMAs
      f32x4 sacc[2][4];
#pragma unroll
      for (int cb = 0; cb < 4; ++cb) {
        f32x4 s0 = {}, s1 = {};
#pragma unroll
        for (int ks = 0; ks < 6; ++ks) {
          bf16x8 kb = ld_bf8(&Ks[(cb * 16 + lr) * 200 + ks * 32 + lg * 8]);
          s0 = __builtin_amdgcn_mfma_f32_16x16x32_bf16(qa[0][ks], kb, s0, 0, 0, 0);
          s1 = __builtin_amdgcn_mfma_f32_16x16x32_bf16(qa[1][ks], kb, s1, 0, 0, 0);
        }
        sacc[0][cb] = s0; sacc[1][cb] = s1;
      }

      if (kt >= 2 * qb) {              // diagonal tiles: causal mask
#pragma unroll
        for (int m = 0; m < 2; ++m)
#pragma unroll
          for (int cb = 0; cb < 4; ++cb)
#pragma unroll
            for (int rg = 0; rg < 4; ++rg) {
              int q_g = q0 + wid * 32 + m * 16 + lg * 4 + rg;
              int kv_g = kt * 64 + cb * 16 + lr;
              if (kv_g > q_g) sacc[m][cb][rg] = -INFINITY;
            }
      }

      float pmax[2][4];
#pragma unroll
      for (int m = 0; m < 2; ++m)
#pragma unroll
        for (int rg = 0; rg < 4; ++rg)
          pmax[m][rg] = fmaxf(fmaxf(sacc[m][0][rg], sacc[m][1][rg]),
                              fmaxf(sacc[m][2][rg], sacc[m][3][rg]));
#pragma unroll
      for (int off = 1; off < 16; off <<= 1)
#pragma unroll
        for (int m = 0; m < 2; ++m)
#pragma unroll
          for (int rg = 0; rg < 4; ++rg)
            pmax[m][rg] = fmaxf(pmax[m][rg], __shfl_xor(pmax[m][rg], off, 64));

#pragma unroll
      for (int m = 0; m < 2; ++m)
#pragma unroll
        for (int rg = 0; rg < 4; ++rg) {
          float mn = fmaxf(m_r[m][rg], pmax[m][rg]);
          float alpha = __expf(m_r[m][rg] - mn);
          m_r[m][rg] = mn;
          l_r[m][rg] *= alpha;
#pragma unroll
          for (int vb = 0; vb < 8; ++vb) acc_o[m][vb][rg] *= alpha;
        }

      float psum[2][4] = {};
#pragma unroll
      for (int m = 0; m < 2; ++m)
#pragma unroll
        for (int cb = 0; cb < 4; ++cb)
#pragma unroll
          for (int rg = 0; rg < 4; ++rg) {
            float pv = __expf(sacc[m][cb][rg] - m_r[m][rg]);
            sacc[m][cb][rg] = pv;
            psum[m][rg] += pv;
          }
#pragma unroll
      for (int off = 1; off < 16; off <<= 1)
#pragma unroll
        for (int m = 0; m < 2; ++m)
#pragma unroll
          for (int rg = 0; rg < 4; ++rg)
            psum[m][rg] += __shfl_xor(psum[m][rg], off, 64);
#pragma unroll
      for (int m = 0; m < 2; ++m)
#pragma unroll
        for (int rg = 0; rg < 4; ++rg) l_r[m][rg] += psum[m][rg];

      // P -> per-wave LDS (same-wave RAW only), rows 0..31
      u16* psw = &Ps[wid * (32 * 88)];
#pragma unroll
      for (int m = 0; m < 2; ++m)
#pragma unroll
        for (int cb = 0; cb < 4; ++cb)
#pragma unroll
          for (int rg = 0; rg < 4; ++rg)
            psw[(m * 16 + lg * 4 + rg) * 88 + cb * 16 + lr] = f2b(sacc[m][cb][rg]);

      bf16x8 pa[2][2];
#pragma unroll
      for (int m = 0; m < 2; ++m)
#pragma unroll
        for (int ks = 0; ks < 2; ++ks)
          pa[m][ks] = ld_bf8(&psw[(m * 16 + lr) * 88 + ks * 32 + lg * 8]);
#pragma unroll
      for (int vb = 0; vb < 8; ++vb) {
#pragma unroll
        for (int ks = 0; ks < 2; ++ks) {
          bf16x8 vv = ld_bf8(&Vs[(vb * 16 + lr) * 72 + ks * 32 + lg * 8]);
          acc_o[0][vb] = __builtin_amdgcn_mfma_f32_16x16x32_bf16(pa[0][ks], vv, acc_o[0][vb], 0, 0, 0);
          acc_o[1][vb] = __builtin_amdgcn_mfma_f32_16x16x32_bf16(pa[1][ks], vv, acc_o[1][vb], 0, 0, 0);
        }
      }
    }

    // epilogue: O[b][s][h*128+d] bf16
#pragma unroll
    for (int m = 0; m < 2; ++m)
#pragma unroll
      for (int vb = 0; vb < 8; ++vb)
#pragma unroll
        for (int rg = 0; rg < 4; ++rg) {
          int s_glob = q0 + wid * 32 + m * 16 + lg * 4 + rg;
          int col = vb * 16 + lr;
          O[((size_t)b * S_LEN + s_glob) * EMB + h * HD + col] =
              f2b(acc_o[m][vb][rg] / l_r[m][rg]);
        }
  }
}

extern "C" void kernel_launch(void* const* d_in, const int* in_sizes, int n_in,
                              void* d_out, int out_size, void* d_ws, size_t ws_size,
                              hipStream_t stream) {
  const float* xf    = (const float*)d_in[0];
  const float* wckvf = (const float*)d_in[1];
  const float* wkf   = (const float*)d_in[2];
  const float* wvf   = (const float*)d_in[3];
  const float* wcqf  = (const float*)d_in[4];
  const float* wqf   = (const float*)d_in[5];
  const float* wqrf  = (const float*)d_in[6];
  const float* wkrf  = (const float*)d_in[7];
  const float* wof   = (const float*)d_in[8];
  (void)in_sizes; (void)n_in; (void)out_size; (void)ws_size;

  u16* ws = (u16*)d_ws;
  size_t off = 0;
  auto alloc = [&](size_t n) -> u16* { u16* p = ws + off; off += n; return p; };
  u16* XB     = alloc(8388608);   // x bf16 [4096,2048]
  u16* WCKV_T = alloc(1048576);   // [512,2048]
  u16* WK_T   = alloc(1048576);   // [2048,512]
  u16* WV_T   = alloc(1048576);   // [2048,512]
  u16* WCQ_T  = alloc(1048576);   // [512,2048]
  u16* WQ_T   = alloc(1048576);   // [2048,512]
  u16* WQR_T  = alloc(524288);    // [1024,512]
  u16* WKR_T  = alloc(131072);    // [64,2048]
  u16* WO_T   = alloc(4194304);   // [2048,2048]
  u16* CKV    = alloc(2097152);   // [4096,512]
  u16* CQ     = alloc(2097152);
  u16* QR     = alloc(4194304);   // [4096,1024]
  u16* KR     = alloc(262144);    // [4096,64]
  u16* QCAT   = alloc(12582912);  // [B,H,S,192]
  u16* KCAT   = alloc(12582912);
  u16* VT     = alloc(8388608);   // [B,H,128,S]
  u16* AOUT   = alloc(8388608);   // [4096,2048]
  float* COS_T = (float*)alloc(131072);
  float* SIN_T = (float*)alloc(131072);

  f2b_kernel<<<8192, 256, 0, stream>>>(xf, XB, 2097152);

  // transpose_f2b(in, out, K, N) with in = [K][N]; grid = dim3(N/64, K/64).
  transpose_f2b_kernel<<<dim3(8, 32),  256, 0, stream>>>(wckvf, WCKV_T, 2048, 512);
  transpose_f2b_kernel<<<dim3(32, 8),  256, 0, stream>>>(wkf,   WK_T,   512, 2048);
  transpose_f2b_kernel<<<dim3(32, 8),  256, 0, stream>>>(wvf,   WV_T,   512, 2048);
  transpose_f2b_kernel<<<dim3(8, 32),  256, 0, stream>>>(wcqf,  WCQ_T,  2048, 512);
  transpose_f2b_kernel<<<dim3(32, 8),  256, 0, stream>>>(wqf,   WQ_T,   512, 2048);
  transpose_f2b_kernel<<<dim3(16, 8),  256, 0, stream>>>(wqrf,  WQR_T,  512, 1024);
  transpose_f2b_kernel<<<dim3(1, 32),  256, 0, stream>>>(wkrf,  WKR_T,  2048, 64);
  transpose_f2b_kernel<<<dim3(32, 32), 256, 0, stream>>>(wof,   WO_T,   2048, 2048);

  rope_table_kernel<<<256, 256, 0, stream>>>(COS_T, SIN_T);

  const float SC = 0.07216878364870323f;  // 1/sqrt(192)
  gemm_bt_kernel<0><<<dim3(4, 32),  256, 0, stream>>>(XB,  WCKV_T, CKV,   4096, 512,  2048, 0,   1.0f);
  gemm_bt_kernel<0><<<dim3(4, 32),  256, 0, stream>>>(XB,  WCQ_T,  CQ,    4096, 512,  2048, 0,   1.0f);
  gemm_bt_kernel<2><<<dim3(16, 32), 256, 0, stream>>>(CKV, WK_T,   KCAT,  4096, 2048, 512,  192, 1.0f);
  gemm_bt_kernel<3><<<dim3(16, 32), 256, 0, stream>>>(CKV, WV_T,   VT,    4096, 2048, 512,  0,   1.0f);
  gemm_bt_kernel<2><<<dim3(16, 32), 256, 0, stream>>>(CQ,  WQ_T,   QCAT,  4096, 2048, 512,  192, SC);
  gemm_bt_kernel<0><<<dim3(8, 32),  256, 0, stream>>>(CQ,  WQR_T,  QR,    4096, 1024, 512,  0,   1.0f);
  gemm_bt_kernel<0><<<dim3(1, 32),  256, 0, stream>>>(XB,  WKR_T,  KR,    4096, 64,   2048, 0,   1.0f);

  rope_assemble_kernel<<<8192, 256, 0, stream>>>(QR, KR, COS_T, SIN_T, QCAT, KCAT);

  attn_kernel<<<dim3(8, 16, 2), 256, 0, stream>>>(QCAT, KCAT, VT, AOUT);

  gemm_bt_kernel<1><<<dim3(16, 32), 256, 0, stream>>>(AOUT, WO_T, d_out, 4096, 2048, 2048, 0, 1.0f);
}

// Round 9
// 289.418 us; speedup vs baseline: 3.6290x; 1.2606x over previous
//
#include <hip/hip_runtime.h>

// MLA v3 forward, MI355X/gfx950. Round 9 (= round 8 with comment-backslash
// compile fix; no functional change).
// - GEMMs fused by weight concatenation (transposed weights [N][K] adjacent
//   in ws): G1 x@[w_ckv|w_cq|w_kr] N=1088; G2 ckv@[w_k|w_v] N=4096;
//   G3 cq@[w_q|w_qr] N=3072; G4 attn@w_o. LDS double-buffer, 1 barrier/iter,
//   global_load_lds(16B), source-side XOR swizzle.
// - Attention: round-4 8-wave QBLK=128 body (VGPR 88), grid 512 single-tile
//   blocks, balanced qb decode -> 2 blocks/CU co-resident.

typedef unsigned short u16;
typedef __attribute__((ext_vector_type(8))) short s16x8;
typedef __attribute__((ext_vector_type(4))) float f32x4;
typedef __attribute__((ext_vector_type(8))) __bf16 bf16x8;
typedef __attribute__((ext_vector_type(4))) u16 u16x4;

#define S_LEN 2048
#define NH 16
#define HD 128
#define DQK 192
#define EMB 2048

#define GLOAD_LDS16(g, l)                                                      \
  __builtin_amdgcn_global_load_lds(                                            \
      (const __attribute__((address_space(1))) unsigned int*)(g),              \
      (__attribute__((address_space(3))) unsigned int*)(l), 16, 0, 0)

__device__ __forceinline__ u16 f2b(float f) {
  unsigned u = __builtin_bit_cast(unsigned, f);
  u += 0x7FFFu + ((u >> 16) & 1u);           // RNE to bf16
  return (u16)(u >> 16);
}
__device__ __forceinline__ float b2f(u16 v) {
  unsigned u = ((unsigned)v) << 16;
  return __builtin_bit_cast(float, u);
}
__device__ __forceinline__ bf16x8 ld_bf8(const u16* p) {
  return __builtin_bit_cast(bf16x8, *(const s16x8*)p);
}

__global__ __launch_bounds__(256) void f2b_kernel(const float* __restrict__ in,
                                                  u16* __restrict__ out, int n4) {
  int i = blockIdx.x * 256 + threadIdx.x;
  if (i >= n4) return;
  f32x4 v = *(const f32x4*)(in + (size_t)i * 4);
  u16x4 o = { f2b(v[0]), f2b(v[1]), f2b(v[2]), f2b(v[3]) };
  *(u16x4*)(out + (size_t)i * 4) = o;
}

// in: f32 [K][N] row-major -> out: bf16 [N][K] row-major. 64x64 tiles.
// Grid must be dim3(N/64, K/64).
__global__ __launch_bounds__(256) void transpose_f2b_kernel(const float* __restrict__ in,
                                                            u16* __restrict__ out,
                                                            int K, int N) {
  __shared__ u16 T[64 * 72];
  const int n0 = blockIdx.x * 64, k0 = blockIdx.y * 64;
  const int t = threadIdx.x;
#pragma unroll
  for (int r = 0; r < 4; ++r) {
    int kl = (t >> 4) + r * 16, nl = (t & 15) * 4;
    f32x4 v = *(const f32x4*)(in + (size_t)(k0 + kl) * N + n0 + nl);
#pragma unroll
    for (int j = 0; j < 4; ++j) T[(nl + j) * 72 + kl] = f2b(v[j]);
  }
  __syncthreads();
#pragma unroll
  for (int r = 0; r < 2; ++r) {
    int chunk = t + r * 256, nr = chunk >> 3, kc = (chunk & 7) * 8;
    *(s16x8*)(out + (size_t)(n0 + nr) * K + k0 + kc) = *(const s16x8*)(&T[nr * 72 + kc]);
  }
}

__global__ __launch_bounds__(256) void rope_table_kernel(float* __restrict__ cosT,
                                                         float* __restrict__ sinT) {
  int id = blockIdx.x * 256 + threadIdx.x;   // S_LEN*32
  int s = id >> 5, i = id & 31;
  float inv = exp2f(-(float)i * (13.287712379549449f / 32.0f));
  float ang = (float)s * inv;
  cosT[id] = cosf(ang);
  sinT[id] = sinf(ang);
}

// C = A[M,K](lda) @ BT[N,K]^T, bf16 in, fp32 accum. 128x128 tile, BK=64.
// LDS double-buffer, 1 barrier/iter; global_load_lds 16B, source-swizzled.
// MODE 0: bf16 [M,N]->Cout; MODE 1: fp32 [M,N]->Cout;
// MODE 4: col<2048 -> KCAT(Cout) [b,h,s,192]; col>=2048 -> VT(Cout2) [b,h,d,s];
// MODE 5: col<2048 -> QCAT(Cout) [b,h,s,192] scaled; col>=2048 -> QR(Cout2) [M,1024].
template<int MODE>
__global__ __launch_bounds__(256) void gemm_bt_kernel(const u16* __restrict__ A,
                                                      int lda,
                                                      const u16* __restrict__ BT,
                                                      void* __restrict__ Cout,
                                                      void* __restrict__ Cout2,
                                                      int M, int N, int K,
                                                      float scale) {
  __shared__ __align__(16) u16 As[2][128 * 64];
  __shared__ __align__(16) u16 Bs[2][128 * 64];
  const int t = threadIdx.x;
  const int lane = t & 63, wid = t >> 6;
  const int wr = (wid >> 1) * 64, wc = (wid & 1) * 64;
  const int bm0 = blockIdx.y * 128, bn0 = blockIdx.x * 128;
  const int lr = lane & 15, lg = lane >> 4;

  auto stage = [&](int k0, int buf) {
#pragma unroll
    for (int r = 0; r < 4; ++r) {            // 1024 chunks of 16B each for A and B
      int chunk = t + r * 256;
      int row = chunk >> 3, kcs = (chunk & 7) * 8;
      int kcg = kcs ^ ((row & 7) << 3);      // inverse swizzle on SOURCE
      GLOAD_LDS16(A + (size_t)(bm0 + row) * lda + k0 + kcg, &As[buf][chunk * 8]);
      GLOAD_LDS16(BT + (size_t)(bn0 + row) * K + k0 + kcg, &Bs[buf][chunk * 8]);
    }
  };

  f32x4 acc[4][4] = {};
  const int nt = K >> 6;
  stage(0, 0);
  for (int tk = 0; tk < nt; ++tk) {
    const int cur = tk & 1;
    __syncthreads();                         // stage(tk) complete; compute(tk-1) done
    if (tk + 1 < nt) stage((tk + 1) << 6, cur ^ 1);   // hides under compute(tk)
#pragma unroll
    for (int kk = 0; kk < 2; ++kk) {
      bf16x8 af[4], bfr[4];
      const int kbase = kk * 32 + lg * 8;
#pragma unroll
      for (int m = 0; m < 4; ++m) {
        int row = wr + m * 16 + lr;
        af[m] = ld_bf8(&As[cur][row * 64 + (kbase ^ ((row & 7) << 3))]);
      }
#pragma unroll
      for (int n = 0; n < 4; ++n) {
        int row = wc + n * 16 + lr;
        bfr[n] = ld_bf8(&Bs[cur][row * 64 + (kbase ^ ((row & 7) << 3))]);
      }
#pragma unroll
      for (int m = 0; m < 4; ++m)
#pragma unroll
        for (int n = 0; n < 4; ++n)
          acc[m][n] = __builtin_amdgcn_mfma_f32_16x16x32_bf16(af[m], bfr[n], acc[m][n], 0, 0, 0);
    }
  }

  // C/D layout: col = lane&15, row = (lane>>4)*4 + reg
#pragma unroll
  for (int m = 0; m < 4; ++m)
#pragma unroll
    for (int n = 0; n < 4; ++n)
#pragma unroll
      for (int rg = 0; rg < 4; ++rg) {
        int row = bm0 + wr + m * 16 + lg * 4 + rg;
        int col = bn0 + wc + n * 16 + lr;
        if (col >= N) continue;
        float v = acc[m][n][rg];
        if (MODE == 0) {
          ((u16*)Cout)[(size_t)row * N + col] = f2b(v * scale);
        } else if (MODE == 1) {
          ((float*)Cout)[(size_t)row * N + col] = v * scale;
        } else if (MODE == 4) {
          int bb = row >> 11, s = row & 2047;
          if (col < 2048) {
            int h = col >> 7, d = col & 127;
            ((u16*)Cout)[((size_t)(bb * NH + h) * S_LEN + s) * DQK + d] = f2b(v);
          } else {
            int c2 = col - 2048, h = c2 >> 7, d = c2 & 127;
            ((u16*)Cout2)[((size_t)(bb * NH + h) * HD + d) * S_LEN + s] = f2b(v);
          }
        } else {  // MODE 5
          int bb = row >> 11, s = row & 2047;
          if (col < 2048) {
            int h = col >> 7, d = col & 127;
            ((u16*)Cout)[((size_t)(bb * NH + h) * S_LEN + s) * DQK + d] = f2b(v * scale);
          } else {
            ((u16*)Cout2)[(size_t)row * 1024 + (col - 2048)] = f2b(v);
          }
        }
      }
}

// Fill rope halves of Qcat/Kcat. kr lives in CC cols 1024..1087 (stride 1088).
__global__ __launch_bounds__(256) void rope_assemble_kernel(const u16* __restrict__ qr,
                                                            const u16* __restrict__ cc,
                                                            const float* __restrict__ cosT,
                                                            const float* __restrict__ sinT,
                                                            u16* __restrict__ Qcat,
                                                            u16* __restrict__ Kcat) {
  int id = blockIdx.x * 256 + threadIdx.x;   // B*H*S*32 = 2^21
  int i = id & 31;
  int s = (id >> 5) & 2047;
  int h = (id >> 16) & 15;
  int b = id >> 20;
  float c = cosT[(s << 5) + i], sn = sinT[(s << 5) + i];
  const float SC = 0.07216878364870323f;     // 1/sqrt(192)

  size_t qbase = ((size_t)b * S_LEN + s) * 1024 + h * 64 + 2 * i;
  float qe = b2f(qr[qbase]), qo = b2f(qr[qbase + 1]);
  size_t obase = ((size_t)(b * NH + h) * S_LEN + s) * DQK + HD + 2 * i;
  Qcat[obase]     = f2b((qe * c - qo * sn) * SC);
  Qcat[obase + 1] = f2b((qe * sn + qo * c) * SC);

  size_t kbase = ((size_t)b * S_LEN + s) * 1088 + 1024 + 2 * i;
  float ke = b2f(cc[kbase]), ko = b2f(cc[kbase + 1]);
  Kcat[obase]     = f2b(ke * c - ko * sn);
  Kcat[obase + 1] = f2b(ke * sn + ko * c);
}

// Flash attention, causal. Round-4 body (8 waves, QBLK=128, kv tile 64).
// Grid = 512 flat blocks; decode gives one q-tile per block with balanced
// pairing (p8<8 -> qb=p8 ; p8>=8 -> qb=23-p8) so big+small tiles co-reside.
__global__ __launch_bounds__(512, 2) void attn_kernel(const u16* __restrict__ Q,
                                                      const u16* __restrict__ K,
                                                      const u16* __restrict__ VT,
                                                      u16* __restrict__ O) {
  __shared__ u16 Ks[64 * 200];    // [kv][d0..191]
  __shared__ u16 Vs[128 * 72];    // [d][kv0..63]
  __shared__ u16 Ps[8 * 16 * 88]; // per-wave [q][kv]
  const int id = blockIdx.x;
  const int p8 = id >> 5, hb = id & 31;
  const int h = hb & 15, b = hb >> 4;
  const int qb = (p8 < 8) ? p8 : 23 - p8;
  const int q0 = qb * 128;
  const int t = threadIdx.x, lane = t & 63, wid = t >> 6;
  const int lr = lane & 15, lg = lane >> 4;
  const size_t qk_head = (size_t)(b * NH + h) * S_LEN * DQK;
  const size_t vt_head = (size_t)(b * NH + h) * HD * S_LEN;

  s16x8 kst[3], vst[2];
  auto gload = [&](int kt) {
#pragma unroll
    for (int r = 0; r < 3; ++r) {
      int chunk = t + r * 512, row = chunk / 24, cc = chunk % 24;
      kst[r] = *(const s16x8*)(K + qk_head + (size_t)(kt * 64 + row) * DQK + cc * 8);
    }
#pragma unroll
    for (int r = 0; r < 2; ++r) {
      int chunk = t + r * 512, d = chunk >> 3, cc = chunk & 7;
      vst[r] = *(const s16x8*)(VT + vt_head + (size_t)d * S_LEN + kt * 64 + cc * 8);
    }
  };
  auto swr = [&]() {
#pragma unroll
    for (int r = 0; r < 3; ++r) {
      int chunk = t + r * 512, row = chunk / 24, cc = chunk % 24;
      *(s16x8*)(&Ks[row * 200 + cc * 8]) = kst[r];
    }
#pragma unroll
    for (int r = 0; r < 2; ++r) {
      int chunk = t + r * 512, d = chunk >> 3, cc = chunk & 7;
      *(s16x8*)(&Vs[d * 72 + cc * 8]) = vst[r];
    }
  };

  bf16x8 qa[6];
  {
    const u16* qrow = Q + qk_head + (size_t)(q0 + wid * 16 + lr) * DQK;
#pragma unroll
    for (int ks = 0; ks < 6; ++ks) qa[ks] = ld_bf8(qrow + ks * 32 + lg * 8);
  }

  f32x4 acc_o[8] = {};
  float m_r[4] = { -INFINITY, -INFINITY, -INFINITY, -INFINITY };
  float l_r[4] = { 0.f, 0.f, 0.f, 0.f };

  const int nt = 2 * qb + 2;
  gload(0);
#pragma unroll 1
  for (int kt = 0; kt < nt; ++kt) {
    __syncthreads();                 // all waves done reading previous tile
    swr();                           // stage tile kt
    if (kt + 1 < nt) gload(kt + 1);  // prefetch next
    __syncthreads();                 // tile kt visible

    f32x4 sacc[4];
#pragma unroll
    for (int cb = 0; cb < 4; ++cb) {
      f32x4 sv = {};
#pragma unroll
      for (int ks = 0; ks < 6; ++ks) {
        bf16x8 kb = ld_bf8(&Ks[(cb * 16 + lr) * 200 + ks * 32 + lg * 8]);
        sv = __builtin_amdgcn_mfma_f32_16x16x32_bf16(qa[ks], kb, sv, 0, 0, 0);
      }
      sacc[cb] = sv;
    }

    if (kt >= 2 * qb) {              // diagonal tiles: causal mask
#pragma unroll
      for (int cb = 0; cb < 4; ++cb)
#pragma unroll
        for (int rg = 0; rg < 4; ++rg) {
          int q_g = q0 + wid * 16 + lg * 4 + rg;
          int kv_g = kt * 64 + cb * 16 + lr;
          if (kv_g > q_g) sacc[cb][rg] = -INFINITY;
        }
    }

    float pmax[4];
#pragma unroll
    for (int rg = 0; rg < 4; ++rg)
      pmax[rg] = fmaxf(fmaxf(sacc[0][rg], sacc[1][rg]), fmaxf(sacc[2][rg], sacc[3][rg]));
#pragma unroll
    for (int off = 1; off < 16; off <<= 1)
#pragma unroll
      for (int rg = 0; rg < 4; ++rg)
        pmax[rg] = fmaxf(pmax[rg], __shfl_xor(pmax[rg], off, 64));

    float alpha[4];
#pragma unroll
    for (int rg = 0; rg < 4; ++rg) {
      float mn = fmaxf(m_r[rg], pmax[rg]);
      alpha[rg] = __expf(m_r[rg] - mn);
      m_r[rg] = mn;
      l_r[rg] *= alpha[rg];
    }
#pragma unroll
    for (int vb = 0; vb < 8; ++vb)
#pragma unroll
      for (int rg = 0; rg < 4; ++rg)
        acc_o[vb][rg] *= alpha[rg];

    float psum[4] = { 0.f, 0.f, 0.f, 0.f };
#pragma unroll
    for (int cb = 0; cb < 4; ++cb)
#pragma unroll
      for (int rg = 0; rg < 4; ++rg) {
        float pv = __expf(sacc[cb][rg] - m_r[rg]);
        sacc[cb][rg] = pv;
        psum[rg] += pv;
      }
#pragma unroll
    for (int off = 1; off < 16; off <<= 1)
#pragma unroll
      for (int rg = 0; rg < 4; ++rg)
        psum[rg] += __shfl_xor(psum[rg], off, 64);
#pragma unroll
    for (int rg = 0; rg < 4; ++rg) l_r[rg] += psum[rg];

    // P -> per-wave LDS (same-wave RAW only)
    u16* psw = &Ps[wid * (16 * 88)];
#pragma unroll
    for (int cb = 0; cb < 4; ++cb)
#pragma unroll
      for (int rg = 0; rg < 4; ++rg)
        psw[(lg * 4 + rg) * 88 + cb * 16 + lr] = f2b(sacc[cb][rg]);

    bf16x8 pa[2];
#pragma unroll
    for (int ks = 0; ks < 2; ++ks) pa[ks] = ld_bf8(&psw[lr * 88 + ks * 32 + lg * 8]);
#pragma unroll
    for (int vb = 0; vb < 8; ++vb) {
#pragma unroll
      for (int ks = 0; ks < 2; ++ks) {
        bf16x8 vv = ld_bf8(&Vs[(vb * 16 + lr) * 72 + ks * 32 + lg * 8]);
        acc_o[vb] = __builtin_amdgcn_mfma_f32_16x16x32_bf16(pa[ks], vv, acc_o[vb], 0, 0, 0);
      }
    }
  }

  // epilogue: O[b][s][h*128+d] bf16
#pragma unroll
  for (int vb = 0; vb < 8; ++vb)
#pragma unroll
    for (int rg = 0; rg < 4; ++rg) {
      int s_glob = q0 + wid * 16 + lg * 4 + rg;
      int col = vb * 16 + lr;
      O[((size_t)b * S_LEN + s_glob) * EMB + h * HD + col] = f2b(acc_o[vb][rg] / l_r[rg]);
    }
}

extern "C" void kernel_launch(void* const* d_in, const int* in_sizes, int n_in,
                              void* d_out, int out_size, void* d_ws, size_t ws_size,
                              hipStream_t stream) {
  const float* xf    = (const float*)d_in[0];
  const float* wckvf = (const float*)d_in[1];
  const float* wkf   = (const float*)d_in[2];
  const float* wvf   = (const float*)d_in[3];
  const float* wcqf  = (const float*)d_in[4];
  const float* wqf   = (const float*)d_in[5];
  const float* wqrf  = (const float*)d_in[6];
  const float* wkrf  = (const float*)d_in[7];
  const float* wof   = (const float*)d_in[8];
  (void)in_sizes; (void)n_in; (void)out_size; (void)ws_size;

  u16* ws = (u16*)d_ws;
  size_t off = 0;
  auto alloc = [&](size_t n) -> u16* { u16* p = ws + off; off += n; return p; };
  u16* XB     = alloc(8388608);   // x bf16 [4096,2048]
  // W1_T group [1088,2048]: wckv rows 0..511, wcq rows 512..1023, wkr rows 1024..1087
  u16* WCKV_T = alloc(1048576);   // [512,2048]
  u16* WCQ_T  = alloc(1048576);   // [512,2048]
  u16* WKR_T  = alloc(131072);    // [64,2048]
  // WKV_T group [4096,512]: wk rows 0..2047, wv rows 2048..4095
  u16* WK_T   = alloc(1048576);   // [2048,512]
  u16* WV_T   = alloc(1048576);   // [2048,512]
  // WQQR_T group [3072,512]: wq rows 0..2047, wqr rows 2048..3071
  u16* WQ_T   = alloc(1048576);   // [2048,512]
  u16* WQR_T  = alloc(524288);    // [1024,512]
  u16* WO_T   = alloc(4194304);   // [2048,2048]
  u16* CC     = alloc(4456448);   // [4096,1088]: ckv | cq | kr
  u16* QR     = alloc(4194304);   // [4096,1024]
  u16* QCAT   = alloc(12582912);  // [B,H,S,192]
  u16* KCAT   = alloc(12582912);
  u16* VT     = alloc(8388608);   // [B,H,128,S]
  u16* AOUT   = alloc(8388608);   // [4096,2048]
  float* COS_T = (float*)alloc(131072);
  float* SIN_T = (float*)alloc(131072);
  (void)WCQ_T; (void)WKR_T; (void)WV_T; (void)WQR_T;

  f2b_kernel<<<8192, 256, 0, stream>>>(xf, XB, 2097152);

  // transpose_f2b(in, out, K, N) with in = [K][N]; grid = dim3(N/64, K/64).
  transpose_f2b_kernel<<<dim3(8, 32),  256, 0, stream>>>(wckvf, WCKV_T, 2048, 512);
  transpose_f2b_kernel<<<dim3(8, 32),  256, 0, stream>>>(wcqf,  WCQ_T,  2048, 512);
  transpose_f2b_kernel<<<dim3(1, 32),  256, 0, stream>>>(wkrf,  WKR_T,  2048, 64);
  transpose_f2b_kernel<<<dim3(32, 8),  256, 0, stream>>>(wkf,   WK_T,   512, 2048);
  transpose_f2b_kernel<<<dim3(32, 8),  256, 0, stream>>>(wvf,   WV_T,   512, 2048);
  transpose_f2b_kernel<<<dim3(32, 8),  256, 0, stream>>>(wqf,   WQ_T,   512, 2048);
  transpose_f2b_kernel<<<dim3(16, 8),  256, 0, stream>>>(wqrf,  WQR_T,  512, 1024);
  transpose_f2b_kernel<<<dim3(32, 32), 256, 0, stream>>>(wof,   WO_T,   2048, 2048);

  rope_table_kernel<<<256, 256, 0, stream>>>(COS_T, SIN_T);

  const float SC = 0.07216878364870323f;  // 1/sqrt(192)
  // G1: x @ [w_ckv | w_cq | w_kr]  -> CC [4096,1088]
  gemm_bt_kernel<0><<<dim3(9, 32),  256, 0, stream>>>(XB, 2048, WCKV_T, CC, nullptr,
                                                      4096, 1088, 2048, 1.0f);
  // G2: c_kv @ [w_k | w_v] -> KCAT + VT
  gemm_bt_kernel<4><<<dim3(32, 32), 256, 0, stream>>>(CC, 1088, WK_T, KCAT, VT,
                                                      4096, 4096, 512, 1.0f);
  // G3: c_q @ [w_q | w_qr] -> QCAT(scaled) + QR
  gemm_bt_kernel<5><<<dim3(24, 32), 256, 0, stream>>>(CC + 512, 1088, WQ_T, QCAT, QR,
                                                      4096, 3072, 512, SC);

  rope_assemble_kernel<<<8192, 256, 0, stream>>>(QR, CC, COS_T, SIN_T, QCAT, KCAT);

  attn_kernel<<<512, 512, 0, stream>>>(QCAT, KCAT, VT, AOUT);

  // G4: attn_out @ w_o -> d_out (fp32)
  gemm_bt_kernel<1><<<dim3(16, 32), 256, 0, stream>>>(AOUT, 2048, WO_T, d_out, nullptr,
                                                      4096, 2048, 2048, 1.0f);
}